// Round 1
// baseline (1986.966 us; speedup 1.0000x reference)
//
#include <hip/hip_runtime.h>
#include <hip/hip_bf16.h>

// MoE: B=4,T=2048,D=768,E=8,F=3072,K=2.  N=8192 tokens.
// Plan: router (fp32) -> per-expert buckets; bf16 cast x; bf16 transposed
// weights W1T[E][F][D], W2T[E][D][F]; fused per-expert MLP with MFMA
// 16x16x32 bf16, out accumulated via fp32 atomics (2-way contention).

#define N_TOK 8192
#define D_DIM 768
#define E_EXP 8
#define F_DIM 3072
#define CAP   8192   // per-expert bucket capacity (<= N since top-2 distinct)
#define TM    64     // token-entries per GEMM block
#define FC    64     // f-chunk per outer iteration
#define KSC   256    // d-chunk for x staging

typedef __attribute__((ext_vector_type(8))) short s8v;   // 8 x bf16 (4 VGPR)
typedef __attribute__((ext_vector_type(4))) float f4v;   // MFMA acc
typedef unsigned short u16;
typedef unsigned int   u32;

static __device__ __forceinline__ u16 f2bf(float f) {
    u32 u = __float_as_uint(f);
    u32 r = (u + 0x7fffu + ((u >> 16) & 1u)) >> 16;   // RNE, inputs finite
    return (u16)r;
}

static __device__ __forceinline__ float gelu_exact(float v) {
    return 0.5f * v * (1.0f + erff(v * 0.70710678118654752440f));
}

// ---------------------------------------------------------------------------
// Router: one wave per token. Computes logits (fp32), softmax, top-2,
// scatters (token, gate) to per-expert buckets, and initializes
// out[t][:] = g0*b2[i0][:] + g1*b2[i1][:].
// ---------------------------------------------------------------------------
__global__ __launch_bounds__(256) void moe_router(
    const float* __restrict__ x, const float* __restrict__ Wg,
    const float* __restrict__ bg, const float* __restrict__ b2,
    float* __restrict__ out, int* __restrict__ counts,
    int* __restrict__ tokbuf, float* __restrict__ gatebuf)
{
    const int wave = threadIdx.x >> 6;
    const int lane = threadIdx.x & 63;
    const int t = blockIdx.x * 4 + wave;

    float acc[8];
    #pragma unroll
    for (int e = 0; e < 8; ++e) acc[e] = 0.f;

    const float* xrow = x + (size_t)t * D_DIM + lane * 12;  // 12 d per lane
    #pragma unroll
    for (int i = 0; i < 3; ++i) {
        float4 xv = *(const float4*)(xrow + i * 4);
        float xs[4] = {xv.x, xv.y, xv.z, xv.w};
        #pragma unroll
        for (int j = 0; j < 4; ++j) {
            const int d = lane * 12 + i * 4 + j;
            const float4 w0 = *(const float4*)(Wg + (size_t)d * 8);
            const float4 w1 = *(const float4*)(Wg + (size_t)d * 8 + 4);
            acc[0] += xs[j] * w0.x;  acc[1] += xs[j] * w0.y;
            acc[2] += xs[j] * w0.z;  acc[3] += xs[j] * w0.w;
            acc[4] += xs[j] * w1.x;  acc[5] += xs[j] * w1.y;
            acc[6] += xs[j] * w1.z;  acc[7] += xs[j] * w1.w;
        }
    }
    // full-wave butterfly reduce each logit
    #pragma unroll
    for (int e = 0; e < 8; ++e) {
        float v = acc[e];
        #pragma unroll
        for (int off = 32; off > 0; off >>= 1) v += __shfl_xor(v, off, 64);
        acc[e] = v + bg[e];
    }
    float mx = acc[0];
    #pragma unroll
    for (int e = 1; e < 8; ++e) mx = fmaxf(mx, acc[e]);
    float p[8], s = 0.f;
    #pragma unroll
    for (int e = 0; e < 8; ++e) { p[e] = expf(acc[e] - mx); s += p[e]; }
    const float inv = 1.f / s;
    #pragma unroll
    for (int e = 0; e < 8; ++e) p[e] *= inv;

    int i0 = 0; float g0 = p[0];
    #pragma unroll
    for (int e = 1; e < 8; ++e) if (p[e] > g0) { g0 = p[e]; i0 = e; }  // ties -> low idx, matches top_k
    int i1 = -1; float g1 = -1.f;
    #pragma unroll
    for (int e = 0; e < 8; ++e) if (e != i0 && p[e] > g1) { g1 = p[e]; i1 = e; }

    if (lane == 0) {
        int p0 = atomicAdd(&counts[i0], 1);
        tokbuf[(size_t)i0 * CAP + p0] = t;
        gatebuf[(size_t)i0 * CAP + p0] = g0;
        int p1 = atomicAdd(&counts[i1], 1);
        tokbuf[(size_t)i1 * CAP + p1] = t;
        gatebuf[(size_t)i1 * CAP + p1] = g1;
    }

    // out init = combined b2 bias (expert blocks atomic-add on top)
    const float* ba = b2 + (size_t)i0 * D_DIM + lane * 12;
    const float* bb = b2 + (size_t)i1 * D_DIM + lane * 12;
    float* orow = out + (size_t)t * D_DIM + lane * 12;
    #pragma unroll
    for (int i = 0; i < 3; ++i) {
        float4 a = *(const float4*)(ba + i * 4);
        float4 b = *(const float4*)(bb + i * 4);
        float4 o;
        o.x = g0 * a.x + g1 * b.x;
        o.y = g0 * a.y + g1 * b.y;
        o.z = g0 * a.z + g1 * b.z;
        o.w = g0 * a.w + g1 * b.w;
        *(float4*)(orow + i * 4) = o;
    }
}

// ---------------------------------------------------------------------------
__global__ __launch_bounds__(256) void cvt_x_kernel(
    const float* __restrict__ x, u16* __restrict__ xb)
{
    const size_t i = ((size_t)blockIdx.x * 256 + threadIdx.x) * 8;
    float4 a = *(const float4*)(x + i);
    float4 b = *(const float4*)(x + i + 4);
    union { s8v v; u16 u[8]; } o;
    o.u[0] = f2bf(a.x); o.u[1] = f2bf(a.y); o.u[2] = f2bf(a.z); o.u[3] = f2bf(a.w);
    o.u[4] = f2bf(b.x); o.u[5] = f2bf(b.y); o.u[6] = f2bf(b.z); o.u[7] = f2bf(b.w);
    *(s8v*)(xb + i) = o.v;
}

// src fp32 [E][R][C] -> dst bf16 [E][C][R]
__global__ __launch_bounds__(256) void transpose_cvt(
    const float* __restrict__ src, u16* __restrict__ dst, int R, int C)
{
    __shared__ float tile[32][33];
    const int e  = blockIdx.z;
    const int c0 = blockIdx.x * 32;
    const int r0 = blockIdx.y * 32;
    const float* s = src + (size_t)e * R * C;
    u16* d = dst + (size_t)e * R * C;
    for (int i = threadIdx.y; i < 32; i += 8)
        tile[i][threadIdx.x] = s[(size_t)(r0 + i) * C + c0 + threadIdx.x];
    __syncthreads();
    for (int i = threadIdx.y; i < 32; i += 8)
        d[(size_t)(c0 + i) * R + r0 + threadIdx.x] = f2bf(tile[threadIdx.x][i]);
}

// ---------------------------------------------------------------------------
// Fused expert MLP. Block = 256 thr (4 waves), TM=64 entries, full D out.
// Phase A: h^T[FC f][64 tok] += W1T(A, global) x X(B, LDS); bias+GELU -> hls.
// Phase B: out^T[768 d][64 tok] += W2T(A, global) x h^T(B, LDS).
// Wave w: phase A owns f-tile w; phase B owns dout tiles [12w,12w+12).
// ---------------------------------------------------------------------------
__global__ __launch_bounds__(256, 2) void moe_gemm(
    const u16* __restrict__ xb, const u16* __restrict__ w1t,
    const u16* __restrict__ w2t, const float* __restrict__ b1,
    const int* __restrict__ counts, const int* __restrict__ tokbuf,
    const float* __restrict__ gatebuf, float* __restrict__ out)
{
    const int e = blockIdx.y;
    const int cnt = counts[e];
    if ((int)(blockIdx.x * TM) >= cnt) return;

    __shared__ u16 xls[TM][KSC + 8];   // 33.8 KB, +8 pad -> 2-way (free) banks
    __shared__ u16 hls[TM][FC + 8];    //  9.2 KB
    __shared__ int stok[TM];
    __shared__ float sgate[TM];

    const int tid  = threadIdx.x;
    const int w    = tid >> 6;
    const int lane = tid & 63;
    const int q    = lane >> 4;
    const int ln   = lane & 15;

    if (tid < TM) {
        const int r = blockIdx.x * TM + tid;
        const bool v = r < cnt;
        stok[tid]  = v ? tokbuf[(size_t)e * CAP + r] : 0;     // pad: token 0
        sgate[tid] = v ? gatebuf[(size_t)e * CAP + r] : 0.f;  // pad: gate 0
    }

    f4v acc[12][4];
    #pragma unroll
    for (int mt = 0; mt < 12; ++mt)
        #pragma unroll
        for (int nt = 0; nt < 4; ++nt)
            acc[mt][nt] = (f4v){0.f, 0.f, 0.f, 0.f};

    const u16*  w1e = w1t + (size_t)e * F_DIM * D_DIM;
    const u16*  w2e = w2t + (size_t)e * D_DIM * F_DIM;
    const float* b1e = b1 + (size_t)e * F_DIM;

    const int srow = tid >> 2;        // staging: 4 threads per row
    const int seg  = tid & 3;

    __syncthreads();
    const size_t xrowbase = (size_t)stok[srow] * D_DIM;

    for (int fci = 0; fci < F_DIM / FC; ++fci) {
        const int fc = fci * FC;
        f4v hacc[4];
        #pragma unroll
        for (int nt = 0; nt < 4; ++nt) hacc[nt] = (f4v){0.f, 0.f, 0.f, 0.f};

        for (int ksi = 0; ksi < D_DIM / KSC; ++ksi) {
            const int ks = ksi * KSC;
            __syncthreads();  // protects xls (and hls on first iter) reuse
            {
                // 4 consecutive lanes cover 64B contiguous per row
                const u16* srcp = xb + xrowbase + ks + seg * 8;
                #pragma unroll
                for (int i = 0; i < 8; ++i)
                    *(s8v*)&xls[srow][seg * 8 + 32 * i] = *(const s8v*)(srcp + 32 * i);
            }
            __syncthreads();
            #pragma unroll
            for (int kk = 0; kk < KSC / 32; ++kk) {
                const s8v af = *(const s8v*)(w1e +
                    (size_t)(fc + w * 16 + ln) * D_DIM + ks + kk * 32 + q * 8);
                #pragma unroll
                for (int nt = 0; nt < 4; ++nt) {
                    const s8v bf = *(const s8v*)&xls[nt * 16 + ln][kk * 32 + q * 8];
                    hacc[nt] = __builtin_amdgcn_mfma_f32_16x16x32_bf16(af, bf, hacc[nt], 0, 0, 0);
                }
            }
        }

        // bias + exact GELU, pack bf16, store h[tok][f] (B-operand layout)
        #pragma unroll
        for (int nt = 0; nt < 4; ++nt) {
            const int tokl = nt * 16 + ln;
            u16 us[4];
            #pragma unroll
            for (int r = 0; r < 4; ++r) {
                const int floc = w * 16 + q * 4 + r;   // C-layout row = f
                const float v = hacc[nt][r] + b1e[fc + floc];
                us[r] = f2bf(gelu_exact(v));
            }
            uint2 pk;
            pk.x = (u32)us[0] | ((u32)us[1] << 16);
            pk.y = (u32)us[2] | ((u32)us[3] << 16);
            *(uint2*)&hls[tokl][w * 16 + q * 4] = pk;
        }
        __syncthreads();

        // Phase B: K=FC over f; A (W2T) direct from global, no wave dup
        #pragma unroll
        for (int kk = 0; kk < FC / 32; ++kk) {
            s8v bfr[4];
            #pragma unroll
            for (int nt = 0; nt < 4; ++nt)
                bfr[nt] = *(const s8v*)&hls[nt * 16 + ln][kk * 32 + q * 8];
            #pragma unroll
            for (int mt = 0; mt < 12; ++mt) {
                const s8v af = *(const s8v*)(w2e +
                    (size_t)((w * 12 + mt) * 16 + ln) * F_DIM + fc + kk * 32 + q * 8);
                #pragma unroll
                for (int nt = 0; nt < 4; ++nt)
                    acc[mt][nt] = __builtin_amdgcn_mfma_f32_16x16x32_bf16(af, bfr[nt], acc[mt][nt], 0, 0, 0);
            }
        }
    }

    // epilogue: out[tok][dout] += g * acc  (C-layout: n=token=ln, m=dout=q*4+r)
    #pragma unroll
    for (int nt = 0; nt < 4; ++nt) {
        const int tokl = nt * 16 + ln;
        const int tok = stok[tokl];
        const float g = sgate[tokl];
        float* obase = out + (size_t)tok * D_DIM + q * 4;
        #pragma unroll
        for (int mt = 0; mt < 12; ++mt) {
            #pragma unroll
            for (int r = 0; r < 4; ++r)
                atomicAdd(obase + (w * 12 + mt) * 16 + r, g * acc[mt][nt][r]);
        }
    }
}

// ---------------------------------------------------------------------------
extern "C" void kernel_launch(void* const* d_in, const int* in_sizes, int n_in,
                              void* d_out, int out_size, void* d_ws, size_t ws_size,
                              hipStream_t stream) {
    const float* x  = (const float*)d_in[0];
    const float* Wg = (const float*)d_in[1];
    const float* bg = (const float*)d_in[2];
    const float* W1 = (const float*)d_in[3];
    const float* b1 = (const float*)d_in[4];
    const float* W2 = (const float*)d_in[5];
    const float* b2 = (const float*)d_in[6];
    float* out = (float*)d_out;

    // ws layout (~88.8 MB total)
    char* ws = (char*)d_ws;
    size_t off = 0;
    u16* xb = (u16*)(ws + off);  off += (size_t)N_TOK * D_DIM * sizeof(u16);
    u16* w1t = (u16*)(ws + off); off += (size_t)E_EXP * F_DIM * D_DIM * sizeof(u16);
    u16* w2t = (u16*)(ws + off); off += (size_t)E_EXP * D_DIM * F_DIM * sizeof(u16);
    int* counts = (int*)(ws + off);     off += 256;
    int* tokbuf = (int*)(ws + off);     off += (size_t)E_EXP * CAP * sizeof(int);
    float* gatebuf = (float*)(ws + off); off += (size_t)E_EXP * CAP * sizeof(float);

    hipMemsetAsync(counts, 0, E_EXP * sizeof(int), stream);

    moe_router<<<N_TOK / 4, 256, 0, stream>>>(x, Wg, bg, b2, out, counts, tokbuf, gatebuf);
    cvt_x_kernel<<<(N_TOK * D_DIM) / (256 * 8), 256, 0, stream>>>(x, xb);
    transpose_cvt<<<dim3(F_DIM / 32, D_DIM / 32, E_EXP), dim3(32, 8), 0, stream>>>(W1, w1t, D_DIM, F_DIM);
    transpose_cvt<<<dim3(D_DIM / 32, F_DIM / 32, E_EXP), dim3(32, 8), 0, stream>>>(W2, w2t, F_DIM, D_DIM);
    moe_gemm<<<dim3(CAP / TM, E_EXP), 256, 0, stream>>>(xb, w1t, w2t, b1, counts, tokbuf, gatebuf, out);
}

// Round 2
// 1005.252 us; speedup vs baseline: 1.9766x; 1.9766x over previous
//
#include <hip/hip_runtime.h>
#include <hip/hip_bf16.h>

// MoE: B=4,T=2048,D=768,E=8,F=3072,K=2.  N=8192 tokens, 16384 entries.
// Two-stage MFMA GEMM pipeline (m97 structure):
//   router -> buckets + out=combined b2 bias;  scan -> tight offsets
//   s1: h[entry][f] = GELU(x W1 + b1)   (bf16, tight-packed)
//   s2: out[tok][d] += gate * (h W2)    (fp32 atomics, 2-way contention)

#define N_TOK 8192
#define D_DIM 768
#define E_EXP 8
#define F_DIM 3072
#define CAP   8192

typedef __attribute__((ext_vector_type(8))) short s8v;   // 8 x bf16
typedef __attribute__((ext_vector_type(4))) float f4v;   // MFMA acc
typedef unsigned short u16;
typedef unsigned int   u32;

static __device__ __forceinline__ u16 f2bf(float f) {
    u32 u = __float_as_uint(f);
    return (u16)((u + 0x7fffu + ((u >> 16) & 1u)) >> 16);   // RNE
}
static __device__ __forceinline__ float gelu_exact(float v) {
    return 0.5f * v * (1.0f + erff(v * 0.70710678118654752440f));
}
static __device__ __forceinline__ void gld_lds16(const void* g, void* l) {
    __builtin_amdgcn_global_load_lds(
        (const __attribute__((address_space(1))) void*)g,
        (__attribute__((address_space(3))) void*)l, 16, 0, 0);
}

// ---------------------------------------------------------------------------
// Router: one wave per token (unchanged from R1 — passed).
// ---------------------------------------------------------------------------
__global__ __launch_bounds__(256) void moe_router(
    const float* __restrict__ x, const float* __restrict__ Wg,
    const float* __restrict__ bg, const float* __restrict__ b2,
    float* __restrict__ out, int* __restrict__ counts,
    int* __restrict__ tokbuf, float* __restrict__ gatebuf)
{
    const int wave = threadIdx.x >> 6;
    const int lane = threadIdx.x & 63;
    const int t = blockIdx.x * 4 + wave;

    float acc[8];
    #pragma unroll
    for (int e = 0; e < 8; ++e) acc[e] = 0.f;

    const float* xrow = x + (size_t)t * D_DIM + lane * 12;
    #pragma unroll
    for (int i = 0; i < 3; ++i) {
        float4 xv = *(const float4*)(xrow + i * 4);
        float xs[4] = {xv.x, xv.y, xv.z, xv.w};
        #pragma unroll
        for (int j = 0; j < 4; ++j) {
            const int d = lane * 12 + i * 4 + j;
            const float4 w0 = *(const float4*)(Wg + (size_t)d * 8);
            const float4 w1 = *(const float4*)(Wg + (size_t)d * 8 + 4);
            acc[0] += xs[j] * w0.x;  acc[1] += xs[j] * w0.y;
            acc[2] += xs[j] * w0.z;  acc[3] += xs[j] * w0.w;
            acc[4] += xs[j] * w1.x;  acc[5] += xs[j] * w1.y;
            acc[6] += xs[j] * w1.z;  acc[7] += xs[j] * w1.w;
        }
    }
    #pragma unroll
    for (int e = 0; e < 8; ++e) {
        float v = acc[e];
        #pragma unroll
        for (int off = 32; off > 0; off >>= 1) v += __shfl_xor(v, off, 64);
        acc[e] = v + bg[e];
    }
    float mx = acc[0];
    #pragma unroll
    for (int e = 1; e < 8; ++e) mx = fmaxf(mx, acc[e]);
    float p[8], s = 0.f;
    #pragma unroll
    for (int e = 0; e < 8; ++e) { p[e] = expf(acc[e] - mx); s += p[e]; }
    const float inv = 1.f / s;
    #pragma unroll
    for (int e = 0; e < 8; ++e) p[e] *= inv;

    int i0 = 0; float g0 = p[0];
    #pragma unroll
    for (int e = 1; e < 8; ++e) if (p[e] > g0) { g0 = p[e]; i0 = e; }
    int i1 = -1; float g1 = -1.f;
    #pragma unroll
    for (int e = 0; e < 8; ++e) if (e != i0 && p[e] > g1) { g1 = p[e]; i1 = e; }

    if (lane == 0) {
        int p0 = atomicAdd(&counts[i0], 1);
        tokbuf[(size_t)i0 * CAP + p0] = t;
        gatebuf[(size_t)i0 * CAP + p0] = g0;
        int p1 = atomicAdd(&counts[i1], 1);
        tokbuf[(size_t)i1 * CAP + p1] = t;
        gatebuf[(size_t)i1 * CAP + p1] = g1;
    }

    const float* ba = b2 + (size_t)i0 * D_DIM + lane * 12;
    const float* bb = b2 + (size_t)i1 * D_DIM + lane * 12;
    float* orow = out + (size_t)t * D_DIM + lane * 12;
    #pragma unroll
    for (int i = 0; i < 3; ++i) {
        float4 a = *(const float4*)(ba + i * 4);
        float4 b = *(const float4*)(bb + i * 4);
        float4 o;
        o.x = g0 * a.x + g1 * b.x;
        o.y = g0 * a.y + g1 * b.y;
        o.z = g0 * a.z + g1 * b.z;
        o.w = g0 * a.w + g1 * b.w;
        *(float4*)(orow + i * 4) = o;
    }
}

__global__ void scan_kernel(const int* __restrict__ counts, int* __restrict__ offs) {
    if (threadIdx.x == 0) {
        int s = 0;
        for (int e = 0; e < E_EXP; ++e) { offs[e] = s; s += counts[e]; }
    }
}

__global__ __launch_bounds__(256) void cvt_x_kernel(
    const float* __restrict__ x, u16* __restrict__ xb)
{
    const size_t i = ((size_t)blockIdx.x * 256 + threadIdx.x) * 8;
    float4 a = *(const float4*)(x + i);
    float4 b = *(const float4*)(x + i + 4);
    union { s8v v; u16 u[8]; } o;
    o.u[0] = f2bf(a.x); o.u[1] = f2bf(a.y); o.u[2] = f2bf(a.z); o.u[3] = f2bf(a.w);
    o.u[4] = f2bf(b.x); o.u[5] = f2bf(b.y); o.u[6] = f2bf(b.z); o.u[7] = f2bf(b.w);
    *(s8v*)(xb + i) = o.v;
}

// src fp32 [E][R][C] -> dst bf16 [E][C][R]
__global__ __launch_bounds__(256) void transpose_cvt(
    const float* __restrict__ src, u16* __restrict__ dst, int R, int C)
{
    __shared__ float tile[32][33];
    const int e  = blockIdx.z;
    const int c0 = blockIdx.x * 32;
    const int r0 = blockIdx.y * 32;
    const float* s = src + (size_t)e * R * C;
    u16* d = dst + (size_t)e * R * C;
    for (int i = threadIdx.y; i < 32; i += 8)
        tile[i][threadIdx.x] = s[(size_t)(r0 + i) * C + c0 + threadIdx.x];
    __syncthreads();
    for (int i = threadIdx.y; i < 32; i += 8)
        d[(size_t)(c0 + i) * R + r0 + threadIdx.x] = f2bf(tile[threadIdx.x][i]);
}

// ---------------------------------------------------------------------------
// Stage 1: h[entry][f] = GELU(x W1 + b1), bf16.
// Tile 128(f) x 128(entry), K=D=768, BK=64. A=w1t rows(f), B=gathered x rows.
// LDS XOR-swizzle: slot (row,c8) holds global chunk c8^(row&7) (conflict-free).
// grid = (nt=64, mt=24, e=8), early exit on nt*128 >= cnt.
// ---------------------------------------------------------------------------
__global__ __launch_bounds__(256) void s1_gemm(
    const u16* __restrict__ xb, const u16* __restrict__ w1t,
    const float* __restrict__ b1, const int* __restrict__ counts,
    const int* __restrict__ offs, const int* __restrict__ tokbuf,
    u16* __restrict__ h)
{
    __shared__ u16 Als[128][64];
    __shared__ u16 Bls[128][64];

    const int e  = blockIdx.z;
    const int nt = blockIdx.x;
    const int mt = blockIdx.y;
    const int cnt = counts[e];
    if (nt * 128 >= cnt) return;

    const int tid  = threadIdx.x;
    const int w    = tid >> 6;
    const int lane = tid & 63;
    const int wm   = w & 1, wn = w >> 1;
    const int q    = lane >> 4, ln = lane & 15;
    const int lrow = lane >> 3;
    const int g8   = (lane & 7) ^ lrow;

    const u16* w1e = w1t + (size_t)e * F_DIM * D_DIM;

    const u16* abase[4];
    const u16* bbase[4];
    #pragma unroll
    for (int it = 0; it < 4; ++it) {
        const int ar = mt * 128 + w * 32 + it * 8 + lrow;
        abase[it] = w1e + (size_t)ar * D_DIM + g8 * 8;
        int br = nt * 128 + w * 32 + it * 8 + lrow;
        if (br >= cnt) br = cnt - 1;                    // clamp pad rows
        const int tok = tokbuf[(size_t)e * CAP + br];
        bbase[it] = xb + (size_t)tok * D_DIM + g8 * 8;
    }

    f4v acc[4][4];
    #pragma unroll
    for (int mi = 0; mi < 4; ++mi)
        #pragma unroll
        for (int ni = 0; ni < 4; ++ni) acc[mi][ni] = (f4v){0.f,0.f,0.f,0.f};

    for (int ks = 0; ks < D_DIM; ks += 64) {
        __syncthreads();
        #pragma unroll
        for (int it = 0; it < 4; ++it) {
            gld_lds16(abase[it] + ks, &Als[w * 32 + it * 8][0]);
            gld_lds16(bbase[it] + ks, &Bls[w * 32 + it * 8][0]);
        }
        __syncthreads();
        #pragma unroll
        for (int kk = 0; kk < 2; ++kk) {
            const int col = ((kk * 4 + q) ^ (ln & 7)) * 8;
            s8v af[4], bf[4];
            #pragma unroll
            for (int mi = 0; mi < 4; ++mi)
                af[mi] = *(const s8v*)&Als[wm * 64 + mi * 16 + ln][col];
            #pragma unroll
            for (int ni = 0; ni < 4; ++ni)
                bf[ni] = *(const s8v*)&Bls[wn * 64 + ni * 16 + ln][col];
            #pragma unroll
            for (int mi = 0; mi < 4; ++mi)
                #pragma unroll
                for (int ni = 0; ni < 4; ++ni)
                    acc[mi][ni] = __builtin_amdgcn_mfma_f32_16x16x32_bf16(
                        af[mi], bf[ni], acc[mi][ni], 0, 0, 0);
        }
    }

    // epilogue: bias + GELU -> bf16 h[entry][f]
    const float* b1e = b1 + (size_t)e * F_DIM;
    const int off_e = offs[e];
    #pragma unroll
    for (int ni = 0; ni < 4; ++ni) {
        const int ent = nt * 128 + wn * 64 + ni * 16 + ln;
        if (ent < cnt) {
            u16* hrow = h + (size_t)(off_e + ent) * F_DIM + mt * 128 + wm * 64;
            #pragma unroll
            for (int mi = 0; mi < 4; ++mi) {
                const float4 bv = *(const float4*)&b1e[mt * 128 + wm * 64 + mi * 16 + q * 4];
                u16 us[4];
                us[0] = f2bf(gelu_exact(acc[mi][ni][0] + bv.x));
                us[1] = f2bf(gelu_exact(acc[mi][ni][1] + bv.y));
                us[2] = f2bf(gelu_exact(acc[mi][ni][2] + bv.z));
                us[3] = f2bf(gelu_exact(acc[mi][ni][3] + bv.w));
                uint2 pk;
                pk.x = (u32)us[0] | ((u32)us[1] << 16);
                pk.y = (u32)us[2] | ((u32)us[3] << 16);
                *(uint2*)&hrow[mi * 16 + q * 4] = pk;
            }
        }
    }
}

// ---------------------------------------------------------------------------
// Stage 2: out[tok][d] += gate * (h @ W2).  Tile 128(d) x 128(entry), K=F=3072.
// A = w2t rows(d), B = h rows(entry, sequential).  grid = (nt=64, mt=6, e=8).
// ---------------------------------------------------------------------------
__global__ __launch_bounds__(256) void s2_gemm(
    const u16* __restrict__ h, const u16* __restrict__ w2t,
    const int* __restrict__ counts, const int* __restrict__ offs,
    const int* __restrict__ tokbuf, const float* __restrict__ gatebuf,
    float* __restrict__ out)
{
    __shared__ u16 Als[128][64];
    __shared__ u16 Bls[128][64];
    __shared__ int   stok[128];
    __shared__ float sg[128];

    const int e  = blockIdx.z;
    const int nt = blockIdx.x;
    const int mt = blockIdx.y;
    const int cnt = counts[e];
    if (nt * 128 >= cnt) return;

    const int tid  = threadIdx.x;
    const int w    = tid >> 6;
    const int lane = tid & 63;
    const int wm   = w & 1, wn = w >> 1;
    const int q    = lane >> 4, ln = lane & 15;
    const int lrow = lane >> 3;
    const int g8   = (lane & 7) ^ lrow;

    if (tid < 128) {
        const int ent = nt * 128 + tid;
        const bool v = ent < cnt;
        stok[tid] = v ? tokbuf[(size_t)e * CAP + ent] : 0;
        sg[tid]   = v ? gatebuf[(size_t)e * CAP + ent] : 0.f;
    }

    const u16* w2e = w2t + (size_t)e * D_DIM * F_DIM;
    const int off_e = offs[e];

    const u16* abase[4];
    const u16* bbase[4];
    #pragma unroll
    for (int it = 0; it < 4; ++it) {
        const int ar = mt * 128 + w * 32 + it * 8 + lrow;
        abase[it] = w2e + (size_t)ar * F_DIM + g8 * 8;
        const int br = nt * 128 + w * 32 + it * 8 + lrow;   // may exceed cnt: reads slack, cols guarded
        bbase[it] = h + (size_t)(off_e + br) * F_DIM + g8 * 8;
    }

    f4v acc[4][4];
    #pragma unroll
    for (int mi = 0; mi < 4; ++mi)
        #pragma unroll
        for (int ni = 0; ni < 4; ++ni) acc[mi][ni] = (f4v){0.f,0.f,0.f,0.f};

    for (int ks = 0; ks < F_DIM; ks += 64) {
        __syncthreads();
        #pragma unroll
        for (int it = 0; it < 4; ++it) {
            gld_lds16(abase[it] + ks, &Als[w * 32 + it * 8][0]);
            gld_lds16(bbase[it] + ks, &Bls[w * 32 + it * 8][0]);
        }
        __syncthreads();
        #pragma unroll
        for (int kk = 0; kk < 2; ++kk) {
            const int col = ((kk * 4 + q) ^ (ln & 7)) * 8;
            s8v af[4], bf[4];
            #pragma unroll
            for (int mi = 0; mi < 4; ++mi)
                af[mi] = *(const s8v*)&Als[wm * 64 + mi * 16 + ln][col];
            #pragma unroll
            for (int ni = 0; ni < 4; ++ni)
                bf[ni] = *(const s8v*)&Bls[wn * 64 + ni * 16 + ln][col];
            #pragma unroll
            for (int mi = 0; mi < 4; ++mi)
                #pragma unroll
                for (int ni = 0; ni < 4; ++ni)
                    acc[mi][ni] = __builtin_amdgcn_mfma_f32_16x16x32_bf16(
                        af[mi], bf[ni], acc[mi][ni], 0, 0, 0);
        }
    }

    // epilogue: gate-scaled atomic accumulate into out (router wrote bias)
    #pragma unroll
    for (int ni = 0; ni < 4; ++ni) {
        const int ent_loc = wn * 64 + ni * 16 + ln;
        if (nt * 128 + ent_loc < cnt) {
            const int   tok = stok[ent_loc];
            const float g   = sg[ent_loc];
            float* op = out + (size_t)tok * D_DIM + mt * 128 + wm * 64;
            #pragma unroll
            for (int mi = 0; mi < 4; ++mi) {
                #pragma unroll
                for (int r = 0; r < 4; ++r)
                    atomicAdd(&op[mi * 16 + q * 4 + r], g * acc[mi][ni][r]);
            }
        }
    }
}

// ---------------------------------------------------------------------------
extern "C" void kernel_launch(void* const* d_in, const int* in_sizes, int n_in,
                              void* d_out, int out_size, void* d_ws, size_t ws_size,
                              hipStream_t stream) {
    const float* x  = (const float*)d_in[0];
    const float* Wg = (const float*)d_in[1];
    const float* bg = (const float*)d_in[2];
    const float* W1 = (const float*)d_in[3];
    const float* b1 = (const float*)d_in[4];
    const float* W2 = (const float*)d_in[5];
    const float* b2 = (const float*)d_in[6];
    float* out = (float*)d_out;

    // ws layout (~190 MB)
    char* ws = (char*)d_ws;
    size_t off = 0;
    u16* xb  = (u16*)(ws + off); off += (size_t)N_TOK * D_DIM * sizeof(u16);
    u16* w1t = (u16*)(ws + off); off += (size_t)E_EXP * F_DIM * D_DIM * sizeof(u16);
    u16* w2t = (u16*)(ws + off); off += (size_t)E_EXP * D_DIM * F_DIM * sizeof(u16);
    int* counts = (int*)(ws + off);      off += 64;
    int* offs   = (int*)(ws + off);      off += 64;
    int* tokbuf = (int*)(ws + off);      off += (size_t)E_EXP * CAP * sizeof(int);
    float* gatebuf = (float*)(ws + off); off += (size_t)E_EXP * CAP * sizeof(float);
    u16* h = (u16*)(ws + off);           off += (size_t)(2 * N_TOK + 128) * F_DIM * sizeof(u16);

    hipMemsetAsync(counts, 0, E_EXP * sizeof(int), stream);

    moe_router<<<N_TOK / 4, 256, 0, stream>>>(x, Wg, bg, b2, out, counts, tokbuf, gatebuf);
    scan_kernel<<<1, 64, 0, stream>>>(counts, offs);
    cvt_x_kernel<<<(N_TOK * D_DIM) / (256 * 8), 256, 0, stream>>>(x, xb);
    transpose_cvt<<<dim3(F_DIM / 32, D_DIM / 32, E_EXP), dim3(32, 8), 0, stream>>>(W1, w1t, D_DIM, F_DIM);
    transpose_cvt<<<dim3(D_DIM / 32, F_DIM / 32, E_EXP), dim3(32, 8), 0, stream>>>(W2, w2t, F_DIM, D_DIM);

    s1_gemm<<<dim3(CAP / 128, F_DIM / 128, E_EXP), 256, 0, stream>>>(
        xb, w1t, b1, counts, offs, tokbuf, h);
    s2_gemm<<<dim3(CAP / 128, D_DIM / 128, E_EXP), 256, 0, stream>>>(
        h, w2t, counts, offs, tokbuf, gatebuf, out);
}

// Round 3
// 718.309 us; speedup vs baseline: 2.7662x; 1.3995x over previous
//
#include <hip/hip_runtime.h>
#include <hip/hip_bf16.h>

// MoE: B=4,T=2048,D=768,E=8,F=3072,K=2.  N=8192 tokens, 16384 entries.
// Pre-packed tile pipeline:
//   router -> buckets (tokslot=2t+slot), out = combined b2 bias
//   scan   -> tile table (expert, base) for <=136 entry-tiles
//   pack_w -> W1/W2 as swizzled [128][64] bf16 tiles (GEMM A operands)
//   pack_x -> gathered x as swizzled tiles (s1 B operand)
//   s1     -> h tiles (written directly in s2 B-tile layout), GELU fused
//   s2     -> y[2t+slot][d] = gate * (h W2)   (no atomics)
//   combine-> out += y[2t] + y[2t+1]
// All GEMM staging: contiguous 1KB global_load_lds, zero K-loop addr math.

#define N_TOK 8192
#define D_DIM 768
#define E_EXP 8
#define F_DIM 3072
#define CAP   8192
#define NT_MAX 136          // max entry tiles: 16384/128 + 8 ceil slack

typedef __attribute__((ext_vector_type(8))) short s8v;   // 8 x bf16
typedef __attribute__((ext_vector_type(4))) float f4v;   // MFMA acc
typedef unsigned short u16;
typedef unsigned int   u32;

static __device__ __forceinline__ u16 f2bf(float f) {
    u32 u = __float_as_uint(f);
    return (u16)((u + 0x7fffu + ((u >> 16) & 1u)) >> 16);   // RNE
}
static __device__ __forceinline__ float gelu_exact(float v) {
    return 0.5f * v * (1.0f + erff(v * 0.70710678118654752440f));
}
static __device__ __forceinline__ void gld_lds16(const u16* g, u16* l) {
    __builtin_amdgcn_global_load_lds(
        (const __attribute__((address_space(1))) void*)g,
        (__attribute__((address_space(3))) void*)l, 16, 0, 0);
}

// ---------------------------------------------------------------------------
// Router: one wave per token. tokbuf entry = 2*t + slot.
// ---------------------------------------------------------------------------
__global__ __launch_bounds__(256) void moe_router(
    const float* __restrict__ x, const float* __restrict__ Wg,
    const float* __restrict__ bg, const float* __restrict__ b2,
    float* __restrict__ out, int* __restrict__ counts,
    int* __restrict__ tokbuf, float* __restrict__ gatebuf)
{
    const int wave = threadIdx.x >> 6;
    const int lane = threadIdx.x & 63;
    const int t = blockIdx.x * 4 + wave;

    float acc[8];
    #pragma unroll
    for (int e = 0; e < 8; ++e) acc[e] = 0.f;

    const float* xrow = x + (size_t)t * D_DIM + lane * 12;
    #pragma unroll
    for (int i = 0; i < 3; ++i) {
        float4 xv = *(const float4*)(xrow + i * 4);
        float xs[4] = {xv.x, xv.y, xv.z, xv.w};
        #pragma unroll
        for (int j = 0; j < 4; ++j) {
            const int d = lane * 12 + i * 4 + j;
            const float4 w0 = *(const float4*)(Wg + (size_t)d * 8);
            const float4 w1 = *(const float4*)(Wg + (size_t)d * 8 + 4);
            acc[0] += xs[j] * w0.x;  acc[1] += xs[j] * w0.y;
            acc[2] += xs[j] * w0.z;  acc[3] += xs[j] * w0.w;
            acc[4] += xs[j] * w1.x;  acc[5] += xs[j] * w1.y;
            acc[6] += xs[j] * w1.z;  acc[7] += xs[j] * w1.w;
        }
    }
    #pragma unroll
    for (int e = 0; e < 8; ++e) {
        float v = acc[e];
        #pragma unroll
        for (int off = 32; off > 0; off >>= 1) v += __shfl_xor(v, off, 64);
        acc[e] = v + bg[e];
    }
    float mx = acc[0];
    #pragma unroll
    for (int e = 1; e < 8; ++e) mx = fmaxf(mx, acc[e]);
    float p[8], s = 0.f;
    #pragma unroll
    for (int e = 0; e < 8; ++e) { p[e] = expf(acc[e] - mx); s += p[e]; }
    const float inv = 1.f / s;
    #pragma unroll
    for (int e = 0; e < 8; ++e) p[e] *= inv;

    int i0 = 0; float g0 = p[0];
    #pragma unroll
    for (int e = 1; e < 8; ++e) if (p[e] > g0) { g0 = p[e]; i0 = e; }
    int i1 = -1; float g1 = -1.f;
    #pragma unroll
    for (int e = 0; e < 8; ++e) if (e != i0 && p[e] > g1) { g1 = p[e]; i1 = e; }

    if (lane == 0) {
        int p0 = atomicAdd(&counts[i0], 1);
        tokbuf[(size_t)i0 * CAP + p0] = 2 * t;
        gatebuf[(size_t)i0 * CAP + p0] = g0;
        int p1 = atomicAdd(&counts[i1], 1);
        tokbuf[(size_t)i1 * CAP + p1] = 2 * t + 1;
        gatebuf[(size_t)i1 * CAP + p1] = g1;
    }

    const float* ba = b2 + (size_t)i0 * D_DIM + lane * 12;
    const float* bb = b2 + (size_t)i1 * D_DIM + lane * 12;
    float* orow = out + (size_t)t * D_DIM + lane * 12;
    #pragma unroll
    for (int i = 0; i < 3; ++i) {
        float4 a = *(const float4*)(ba + i * 4);
        float4 b = *(const float4*)(bb + i * 4);
        float4 o;
        o.x = g0 * a.x + g1 * b.x;
        o.y = g0 * a.y + g1 * b.y;
        o.z = g0 * a.z + g1 * b.z;
        o.w = g0 * a.w + g1 * b.w;
        *(float4*)(orow + i * 4) = o;
    }
}

// tile table: for each expert, one tile per 128 entries
__global__ void scan_kernel(const int* __restrict__ counts,
                            int* __restrict__ te, int* __restrict__ tb,
                            int* __restrict__ ntile) {
    if (threadIdx.x == 0) {
        int nt = 0;
        for (int e = 0; e < E_EXP; ++e)
            for (int k = 0; k * 128 < counts[e]; ++k) {
                te[nt] = e; tb[nt] = k * 128; ++nt;
            }
        *ntile = nt;
    }
}

// ---------------------------------------------------------------------------
// pack_w: src fp32 [E][K1][M2] -> swizzled bf16 tiles
//   dst tile ((e*RT + rt)*KC + kc): row r in [0,128) = m = rt*128+r,
//   chunk c8: holds src[k = kc*64 + (c8^(r&7))*8 + jj][m], jj=0..7.
// ---------------------------------------------------------------------------
__global__ __launch_bounds__(256) void pack_w(
    const float* __restrict__ src, u16* __restrict__ dst, int K1, int M2)
{
    __shared__ float ls[64][132];
    const int rt = blockIdx.x, kc = blockIdx.y, e = blockIdx.z;
    const int RT = gridDim.x, KC = gridDim.y;
    const float* se = src + (size_t)e * K1 * M2;
    const int tid = threadIdx.x;

    const int kr = tid >> 2, mq = tid & 3;
    const float* srow = se + (size_t)(kc * 64 + kr) * M2 + rt * 128 + mq * 32;
    #pragma unroll
    for (int it = 0; it < 8; ++it)
        *(float4*)&ls[kr][mq * 32 + it * 4] = *(const float4*)(srow + it * 4);
    __syncthreads();

    u16* dt_ = dst + ((size_t)(e * RT + rt) * KC + kc) * 8192;
    const int rr = tid >> 1, hf = tid & 1;
    #pragma unroll
    for (int j = 0; j < 4; ++j) {
        const int c8 = hf * 4 + j;
        union { s8v v; u16 u[8]; } o;
        #pragma unroll
        for (int jj = 0; jj < 8; ++jj) o.u[jj] = f2bf(ls[c8 * 8 + jj][rr]);
        *(s8v*)&dt_[rr * 64 + ((c8 ^ (rr & 7)) * 8)] = o.v;
    }
}

// ---------------------------------------------------------------------------
// pack_x: gather token rows -> swizzled bf16 tiles (s1 B operand).
// grid (NT_MAX, 12).  Pad rows clamp to last valid entry (finite dup data).
// ---------------------------------------------------------------------------
__global__ __launch_bounds__(256) void pack_x(
    const float* __restrict__ x, const int* __restrict__ counts,
    const int* __restrict__ te, const int* __restrict__ tb,
    const int* __restrict__ ntile, const int* __restrict__ tokbuf,
    u16* __restrict__ xg)
{
    const int bx = blockIdx.x, kc = blockIdx.y;
    if (bx >= *ntile) return;
    const int e = te[bx], base = tb[bx], cnt = counts[e];
    const int tid = threadIdx.x;
    const int r = tid >> 1, hf = tid & 1;
    int ent = base + r; if (ent >= cnt) ent = cnt - 1;
    const int tok = tokbuf[(size_t)e * CAP + ent] >> 1;
    const float* xr = x + (size_t)tok * D_DIM + kc * 64 + hf * 32;
    u16* xt = xg + ((size_t)bx * 12 + kc) * 8192 + r * 64;
    #pragma unroll
    for (int j = 0; j < 4; ++j) {
        float4 a = *(const float4*)(xr + j * 8);
        float4 b = *(const float4*)(xr + j * 8 + 4);
        union { s8v v; u16 u[8]; } o;
        o.u[0] = f2bf(a.x); o.u[1] = f2bf(a.y); o.u[2] = f2bf(a.z); o.u[3] = f2bf(a.w);
        o.u[4] = f2bf(b.x); o.u[5] = f2bf(b.y); o.u[6] = f2bf(b.z); o.u[7] = f2bf(b.w);
        *(s8v*)&xt[((hf * 4 + j) ^ (r & 7)) * 8] = o.v;
    }
}

// ---------------------------------------------------------------------------
// Stage 1: per (entry-tile, f-tile): C[m=f 128][n=entry 128], K=768 (12 steps).
// Staging: contiguous 1KB global_load_lds x8 per wave per step.
// Epilogue: bias + exact GELU -> bf16, written in s2's B-tile layout.
// ---------------------------------------------------------------------------
__global__ __launch_bounds__(256) void s1_gemm(
    const u16* __restrict__ xg, const u16* __restrict__ w1g,
    const float* __restrict__ b1, const int* __restrict__ te,
    const int* __restrict__ ntile, u16* __restrict__ hg)
{
    __shared__ u16 Als[8192];
    __shared__ u16 Bls[8192];
    const int bx = blockIdx.x, by = blockIdx.y;
    if (bx >= *ntile) return;
    const int e = te[bx];

    const int tid  = threadIdx.x;
    const int w    = tid >> 6;
    const int lane = tid & 63;
    const int wm   = w & 1, wn = w >> 1;
    const int q    = lane >> 4, ln = lane & 15;

    const u16* Ap = w1g + ((size_t)(e * 24 + by) * 12) * 8192 + w * 2048 + lane * 8;
    const u16* Bp = xg  + ((size_t)bx * 12) * 8192 + w * 2048 + lane * 8;

    f4v acc[4][4];
    #pragma unroll
    for (int mi = 0; mi < 4; ++mi)
        #pragma unroll
        for (int ni = 0; ni < 4; ++ni) acc[mi][ni] = (f4v){0.f,0.f,0.f,0.f};

    for (int s = 0; s < 12; ++s) {
        __syncthreads();
        #pragma unroll
        for (int it = 0; it < 4; ++it) {
            gld_lds16(Ap + it * 512, &Als[w * 2048 + it * 512]);
            gld_lds16(Bp + it * 512, &Bls[w * 2048 + it * 512]);
        }
        Ap += 8192; Bp += 8192;
        __syncthreads();
        #pragma unroll
        for (int kk = 0; kk < 2; ++kk) {
            const int col = ((kk * 4 + q) ^ (ln & 7)) * 8;
            s8v af[4], bf[4];
            #pragma unroll
            for (int mi = 0; mi < 4; ++mi)
                af[mi] = *(const s8v*)&Als[(wm * 64 + mi * 16 + ln) * 64 + col];
            #pragma unroll
            for (int ni = 0; ni < 4; ++ni)
                bf[ni] = *(const s8v*)&Bls[(wn * 64 + ni * 16 + ln) * 64 + col];
            #pragma unroll
            for (int mi = 0; mi < 4; ++mi)
                #pragma unroll
                for (int ni = 0; ni < 4; ++ni)
                    acc[mi][ni] = __builtin_amdgcn_mfma_f32_16x16x32_bf16(
                        af[mi], bf[ni], acc[mi][ni], 0, 0, 0);
        }
    }

    // epilogue -> hg tile (bx, kc = by*2 + wm), row = entry, swizzled f chunks
    const float* b1e = b1 + (size_t)e * F_DIM + by * 128 + wm * 64;
    u16* ht = hg + ((size_t)bx * 48 + by * 2 + wm) * 8192;
    #pragma unroll
    for (int ni = 0; ni < 4; ++ni) {
        const int rr = wn * 64 + ni * 16 + ln;
        #pragma unroll
        for (int mi = 0; mi < 4; ++mi) {
            const float4 bv = *(const float4*)&b1e[mi * 16 + q * 4];
            u16 us[4];
            us[0] = f2bf(gelu_exact(acc[mi][ni][0] + bv.x));
            us[1] = f2bf(gelu_exact(acc[mi][ni][1] + bv.y));
            us[2] = f2bf(gelu_exact(acc[mi][ni][2] + bv.z));
            us[3] = f2bf(gelu_exact(acc[mi][ni][3] + bv.w));
            uint2 pk;
            pk.x = (u32)us[0] | ((u32)us[1] << 16);
            pk.y = (u32)us[2] | ((u32)us[3] << 16);
            const int c8 = mi * 2 + (q >> 1);
            *(uint2*)&ht[rr * 64 + ((c8 ^ (rr & 7)) * 8) + (q & 1) * 4] = pk;
        }
    }
}

// ---------------------------------------------------------------------------
// Stage 2: per (entry-tile, d-tile): C[m=d 128][n=entry 128], K=3072 (48 steps).
// Epilogue: y[tokslot][d] = gate * C   (plain float4 stores, no atomics).
// ---------------------------------------------------------------------------
__global__ __launch_bounds__(256) void s2_gemm(
    const u16* __restrict__ hg, const u16* __restrict__ w2g,
    const int* __restrict__ counts, const int* __restrict__ te,
    const int* __restrict__ tb, const int* __restrict__ ntile,
    const int* __restrict__ tokbuf, const float* __restrict__ gatebuf,
    float* __restrict__ y)
{
    __shared__ u16 Als[8192];
    __shared__ u16 Bls[8192];
    __shared__ int   sts[128];
    __shared__ float sg[128];
    const int bx = blockIdx.x, by = blockIdx.y;
    if (bx >= *ntile) return;
    const int e = te[bx], base = tb[bx], cnt = counts[e];

    const int tid  = threadIdx.x;
    const int w    = tid >> 6;
    const int lane = tid & 63;
    const int wm   = w & 1, wn = w >> 1;
    const int q    = lane >> 4, ln = lane & 15;

    if (tid < 128) {
        const int ent = base + tid;
        const bool v = ent < cnt;
        sts[tid] = v ? tokbuf[(size_t)e * CAP + ent] : -1;
        sg[tid]  = v ? gatebuf[(size_t)e * CAP + ent] : 0.f;
    }

    const u16* Ap = w2g + ((size_t)(e * 6 + by) * 48) * 8192 + w * 2048 + lane * 8;
    const u16* Bp = hg  + ((size_t)bx * 48) * 8192 + w * 2048 + lane * 8;

    f4v acc[4][4];
    #pragma unroll
    for (int mi = 0; mi < 4; ++mi)
        #pragma unroll
        for (int ni = 0; ni < 4; ++ni) acc[mi][ni] = (f4v){0.f,0.f,0.f,0.f};

    for (int s = 0; s < 48; ++s) {
        __syncthreads();
        #pragma unroll
        for (int it = 0; it < 4; ++it) {
            gld_lds16(Ap + it * 512, &Als[w * 2048 + it * 512]);
            gld_lds16(Bp + it * 512, &Bls[w * 2048 + it * 512]);
        }
        Ap += 8192; Bp += 8192;
        __syncthreads();
        #pragma unroll
        for (int kk = 0; kk < 2; ++kk) {
            const int col = ((kk * 4 + q) ^ (ln & 7)) * 8;
            s8v af[4], bf[4];
            #pragma unroll
            for (int mi = 0; mi < 4; ++mi)
                af[mi] = *(const s8v*)&Als[(wm * 64 + mi * 16 + ln) * 64 + col];
            #pragma unroll
            for (int ni = 0; ni < 4; ++ni)
                bf[ni] = *(const s8v*)&Bls[(wn * 64 + ni * 16 + ln) * 64 + col];
            #pragma unroll
            for (int mi = 0; mi < 4; ++mi)
                #pragma unroll
                for (int ni = 0; ni < 4; ++ni)
                    acc[mi][ni] = __builtin_amdgcn_mfma_f32_16x16x32_bf16(
                        af[mi], bf[ni], acc[mi][ni], 0, 0, 0);
        }
    }

    #pragma unroll
    for (int ni = 0; ni < 4; ++ni) {
        const int rr = wn * 64 + ni * 16 + ln;
        const int ts = sts[rr];
        if (ts >= 0) {
            const float g = sg[rr];
            float* yr = y + (size_t)ts * D_DIM + by * 128 + wm * 64;
            #pragma unroll
            for (int mi = 0; mi < 4; ++mi) {
                float4 o;
                o.x = g * acc[mi][ni][0];
                o.y = g * acc[mi][ni][1];
                o.z = g * acc[mi][ni][2];
                o.w = g * acc[mi][ni][3];
                *(float4*)&yr[mi * 16 + q * 4] = o;
            }
        }
    }
}

__global__ __launch_bounds__(256) void combine_kernel(
    const float* __restrict__ y, float* __restrict__ out)
{
    const int gid = blockIdx.x * 256 + threadIdx.x;
    const int t = gid / 192;
    const int c = (gid - t * 192) * 4;
    const float4 a = *(const float4*)&y[(size_t)(2 * t) * D_DIM + c];
    const float4 b = *(const float4*)&y[(size_t)(2 * t + 1) * D_DIM + c];
    float4 o = *(float4*)&out[(size_t)t * D_DIM + c];
    o.x += a.x + b.x;  o.y += a.y + b.y;
    o.z += a.z + b.z;  o.w += a.w + b.w;
    *(float4*)&out[(size_t)t * D_DIM + c] = o;
}

// ---------------------------------------------------------------------------
extern "C" void kernel_launch(void* const* d_in, const int* in_sizes, int n_in,
                              void* d_out, int out_size, void* d_ws, size_t ws_size,
                              hipStream_t stream) {
    const float* x  = (const float*)d_in[0];
    const float* Wg = (const float*)d_in[1];
    const float* bg = (const float*)d_in[2];
    const float* W1 = (const float*)d_in[3];
    const float* b1 = (const float*)d_in[4];
    const float* W2 = (const float*)d_in[5];
    const float* b2 = (const float*)d_in[6];
    float* out = (float*)d_out;

    // ws layout (~260 MB)
    char* ws = (char*)d_ws;
    size_t off = 0;
    u16* xg  = (u16*)(ws + off); off += (size_t)NT_MAX * 12 * 8192 * sizeof(u16);
    u16* w1g = (u16*)(ws + off); off += (size_t)E_EXP * 24 * 12 * 8192 * sizeof(u16);
    u16* w2g = (u16*)(ws + off); off += (size_t)E_EXP * 6 * 48 * 8192 * sizeof(u16);
    u16* hg  = (u16*)(ws + off); off += (size_t)NT_MAX * 48 * 8192 * sizeof(u16);
    float* y = (float*)(ws + off); off += (size_t)2 * N_TOK * D_DIM * sizeof(float);
    int* tokbuf = (int*)(ws + off);      off += (size_t)E_EXP * CAP * sizeof(int);
    float* gatebuf = (float*)(ws + off); off += (size_t)E_EXP * CAP * sizeof(float);
    int* counts = (int*)(ws + off);      off += 64;
    int* te     = (int*)(ws + off);      off += NT_MAX * sizeof(int);
    int* tb     = (int*)(ws + off);      off += NT_MAX * sizeof(int);
    int* ntile  = (int*)(ws + off);      off += 64;

    hipMemsetAsync(counts, 0, E_EXP * sizeof(int), stream);

    moe_router<<<N_TOK / 4, 256, 0, stream>>>(x, Wg, bg, b2, out, counts, tokbuf, gatebuf);
    scan_kernel<<<1, 64, 0, stream>>>(counts, te, tb, ntile);
    pack_w<<<dim3(24, 12, E_EXP), 256, 0, stream>>>(W1, w1g, D_DIM, F_DIM);
    pack_w<<<dim3(6, 48, E_EXP), 256, 0, stream>>>(W2, w2g, F_DIM, D_DIM);
    pack_x<<<dim3(NT_MAX, 12), 256, 0, stream>>>(x, counts, te, tb, ntile, tokbuf, xg);

    s1_gemm<<<dim3(NT_MAX, 24), 256, 0, stream>>>(xg, w1g, b1, te, ntile, hg);
    s2_gemm<<<dim3(NT_MAX, 6), 256, 0, stream>>>(hg, w2g, counts, te, tb, ntile,
                                                 tokbuf, gatebuf, y);
    combine_kernel<<<(N_TOK * 192) / 256, 256, 0, stream>>>(y, out);
}

// Round 4
// 561.993 us; speedup vs baseline: 3.5356x; 1.2781x over previous
//
#include <hip/hip_runtime.h>
#include <hip/hip_bf16.h>

// MoE: B=4,T=2048,D=768,E=8,F=3072,K=2.  N=8192 tokens, 16384 entries.
// Pipeline:
//   moe_gates  -> per-token records (i0,i1,g0,g1), no atomics
//   moe_scatter-> buckets via wave-ballot aggregation (<=1024 atomics)
//   scan       -> tile table (expert, base) for <=136 entry-tiles
//   pack_w     -> W1/W2 as swizzled [128][64] bf16 tiles (GEMM A operands)
//   pack_x     -> gathered x as swizzled tiles (s1 B operand)
//   s1         -> h tiles (written directly in s2 B-tile layout), GELU fused
//   s2         -> y[2t+slot][d] = gate * (h W2)   (no atomics)
//   combine    -> out = g0*b2[i0] + g1*b2[i1] + y[2t] + y[2t+1]

#define N_TOK 8192
#define D_DIM 768
#define E_EXP 8
#define F_DIM 3072
#define CAP   8192
#define NT_MAX 136          // max entry tiles: 16384/128 + 8 ceil slack

typedef __attribute__((ext_vector_type(8))) short s8v;   // 8 x bf16
typedef __attribute__((ext_vector_type(4))) float f4v;   // MFMA acc
typedef unsigned short u16;
typedef unsigned int   u32;
typedef unsigned long long u64;

static __device__ __forceinline__ u16 f2bf(float f) {
    u32 u = __float_as_uint(f);
    return (u16)((u + 0x7fffu + ((u >> 16) & 1u)) >> 16);   // RNE
}
static __device__ __forceinline__ float gelu_exact(float v) {
    return 0.5f * v * (1.0f + erff(v * 0.70710678118654752440f));
}
static __device__ __forceinline__ void gld_lds16(const u16* g, u16* l) {
    __builtin_amdgcn_global_load_lds(
        (const __attribute__((address_space(1))) void*)g,
        (__attribute__((address_space(3))) void*)l, 16, 0, 0);
}

// ---------------------------------------------------------------------------
// Gates: one wave per token.  Writes rec_idx[t]=i0|i1<<4, rec_g[t]=(g0,g1).
// No atomics, no out writes.
// ---------------------------------------------------------------------------
__global__ __launch_bounds__(256) void moe_gates(
    const float* __restrict__ x, const float* __restrict__ Wg,
    const float* __restrict__ bg, u32* __restrict__ rec_idx,
    float2* __restrict__ rec_g)
{
    const int wave = threadIdx.x >> 6;
    const int lane = threadIdx.x & 63;
    const int t = blockIdx.x * 4 + wave;

    float acc[8];
    #pragma unroll
    for (int e = 0; e < 8; ++e) acc[e] = 0.f;

    const float* xrow = x + (size_t)t * D_DIM + lane * 12;
    #pragma unroll
    for (int i = 0; i < 3; ++i) {
        float4 xv = *(const float4*)(xrow + i * 4);
        float xs[4] = {xv.x, xv.y, xv.z, xv.w};
        #pragma unroll
        for (int j = 0; j < 4; ++j) {
            const int d = lane * 12 + i * 4 + j;
            const float4 w0 = *(const float4*)(Wg + (size_t)d * 8);
            const float4 w1 = *(const float4*)(Wg + (size_t)d * 8 + 4);
            acc[0] += xs[j] * w0.x;  acc[1] += xs[j] * w0.y;
            acc[2] += xs[j] * w0.z;  acc[3] += xs[j] * w0.w;
            acc[4] += xs[j] * w1.x;  acc[5] += xs[j] * w1.y;
            acc[6] += xs[j] * w1.z;  acc[7] += xs[j] * w1.w;
        }
    }
    #pragma unroll
    for (int e = 0; e < 8; ++e) {
        float v = acc[e];
        #pragma unroll
        for (int off = 32; off > 0; off >>= 1) v += __shfl_xor(v, off, 64);
        acc[e] = v + bg[e];
    }
    if (lane == 0) {
        float mx = acc[0];
        #pragma unroll
        for (int e = 1; e < 8; ++e) mx = fmaxf(mx, acc[e]);
        float p[8], s = 0.f;
        #pragma unroll
        for (int e = 0; e < 8; ++e) { p[e] = expf(acc[e] - mx); s += p[e]; }
        const float inv = 1.f / s;
        #pragma unroll
        for (int e = 0; e < 8; ++e) p[e] *= inv;

        int i0 = 0; float g0 = p[0];
        #pragma unroll
        for (int e = 1; e < 8; ++e) if (p[e] > g0) { g0 = p[e]; i0 = e; }
        int i1 = -1; float g1 = -1.f;
        #pragma unroll
        for (int e = 0; e < 8; ++e) if (e != i0 && p[e] > g1) { g1 = p[e]; i1 = e; }

        rec_idx[t] = (u32)i0 | ((u32)i1 << 4);
        rec_g[t] = make_float2(g0, g1);
    }
}

// ---------------------------------------------------------------------------
// Scatter: thread per token, wave-ballot aggregation -> <=8 atomics/wave.
// ---------------------------------------------------------------------------
__global__ __launch_bounds__(256) void moe_scatter(
    const u32* __restrict__ rec_idx, const float2* __restrict__ rec_g,
    int* __restrict__ counts, int* __restrict__ tokbuf,
    float* __restrict__ gatebuf)
{
    const int t = blockIdx.x * 256 + threadIdx.x;
    const int lane = threadIdx.x & 63;
    const u32 pk = rec_idx[t];
    const int i0 = pk & 15, i1 = (pk >> 4) & 15;
    const float2 g = rec_g[t];
    const u64 lmask = ((u64)1 << lane) - 1;

    #pragma unroll
    for (int e = 0; e < 8; ++e) {
        const u64 m0 = __ballot(i0 == e);
        const u64 m1 = __ballot(i1 == e);
        const int c0 = __popcll(m0);
        const int total = c0 + __popcll(m1);
        if (total > 0) {
            int base = 0;
            if (lane == 0) base = atomicAdd(&counts[e], total);
            base = __shfl(base, 0, 64);
            if (i0 == e) {
                const int p = base + __popcll(m0 & lmask);
                tokbuf[(size_t)e * CAP + p] = 2 * t;
                gatebuf[(size_t)e * CAP + p] = g.x;
            }
            if (i1 == e) {
                const int p = base + c0 + __popcll(m1 & lmask);
                tokbuf[(size_t)e * CAP + p] = 2 * t + 1;
                gatebuf[(size_t)e * CAP + p] = g.y;
            }
        }
    }
}

// tile table: for each expert, one tile per 128 entries
__global__ void scan_kernel(const int* __restrict__ counts,
                            int* __restrict__ te, int* __restrict__ tb,
                            int* __restrict__ ntile) {
    if (threadIdx.x == 0) {
        int nt = 0;
        for (int e = 0; e < E_EXP; ++e)
            for (int k = 0; k * 128 < counts[e]; ++k) {
                te[nt] = e; tb[nt] = k * 128; ++nt;
            }
        *ntile = nt;
    }
}

// ---------------------------------------------------------------------------
// pack_w: src fp32 [E][K1][M2] -> swizzled bf16 tiles
// ---------------------------------------------------------------------------
__global__ __launch_bounds__(256) void pack_w(
    const float* __restrict__ src, u16* __restrict__ dst, int K1, int M2)
{
    __shared__ float ls[64][132];
    const int rt = blockIdx.x, kc = blockIdx.y, e = blockIdx.z;
    const int RT = gridDim.x, KC = gridDim.y;
    const float* se = src + (size_t)e * K1 * M2;
    const int tid = threadIdx.x;

    const int kr = tid >> 2, mq = tid & 3;
    const float* srow = se + (size_t)(kc * 64 + kr) * M2 + rt * 128 + mq * 32;
    #pragma unroll
    for (int it = 0; it < 8; ++it)
        *(float4*)&ls[kr][mq * 32 + it * 4] = *(const float4*)(srow + it * 4);
    __syncthreads();

    u16* dt_ = dst + ((size_t)(e * RT + rt) * KC + kc) * 8192;
    const int rr = tid >> 1, hf = tid & 1;
    #pragma unroll
    for (int j = 0; j < 4; ++j) {
        const int c8 = hf * 4 + j;
        union { s8v v; u16 u[8]; } o;
        #pragma unroll
        for (int jj = 0; jj < 8; ++jj) o.u[jj] = f2bf(ls[c8 * 8 + jj][rr]);
        *(s8v*)&dt_[rr * 64 + ((c8 ^ (rr & 7)) * 8)] = o.v;
    }
}

// ---------------------------------------------------------------------------
// pack_x: gather token rows -> swizzled bf16 tiles (s1 B operand).
// ---------------------------------------------------------------------------
__global__ __launch_bounds__(256) void pack_x(
    const float* __restrict__ x, const int* __restrict__ counts,
    const int* __restrict__ te, const int* __restrict__ tb,
    const int* __restrict__ ntile, const int* __restrict__ tokbuf,
    u16* __restrict__ xg)
{
    const int bx = blockIdx.x, kc = blockIdx.y;
    if (bx >= *ntile) return;
    const int e = te[bx], base = tb[bx], cnt = counts[e];
    const int tid = threadIdx.x;
    const int r = tid >> 1, hf = tid & 1;
    int ent = base + r; if (ent >= cnt) ent = cnt - 1;
    const int tok = tokbuf[(size_t)e * CAP + ent] >> 1;
    const float* xr = x + (size_t)tok * D_DIM + kc * 64 + hf * 32;
    u16* xt = xg + ((size_t)bx * 12 + kc) * 8192 + r * 64;
    #pragma unroll
    for (int j = 0; j < 4; ++j) {
        float4 a = *(const float4*)(xr + j * 8);
        float4 b = *(const float4*)(xr + j * 8 + 4);
        union { s8v v; u16 u[8]; } o;
        o.u[0] = f2bf(a.x); o.u[1] = f2bf(a.y); o.u[2] = f2bf(a.z); o.u[3] = f2bf(a.w);
        o.u[4] = f2bf(b.x); o.u[5] = f2bf(b.y); o.u[6] = f2bf(b.z); o.u[7] = f2bf(b.w);
        *(s8v*)&xt[((hf * 4 + j) ^ (r & 7)) * 8] = o.v;
    }
}

// ---------------------------------------------------------------------------
// Stage 1: per (entry-tile, f-tile): C[m=f 128][n=entry 128], K=768 (12 steps).
// ---------------------------------------------------------------------------
__global__ __launch_bounds__(256) void s1_gemm(
    const u16* __restrict__ xg, const u16* __restrict__ w1g,
    const float* __restrict__ b1, const int* __restrict__ te,
    const int* __restrict__ ntile, u16* __restrict__ hg)
{
    __shared__ u16 Als[8192];
    __shared__ u16 Bls[8192];
    const int bx = blockIdx.x, by = blockIdx.y;
    if (bx >= *ntile) return;
    const int e = te[bx];

    const int tid  = threadIdx.x;
    const int w    = tid >> 6;
    const int lane = tid & 63;
    const int wm   = w & 1, wn = w >> 1;
    const int q    = lane >> 4, ln = lane & 15;

    const u16* Ap = w1g + ((size_t)(e * 24 + by) * 12) * 8192 + w * 2048 + lane * 8;
    const u16* Bp = xg  + ((size_t)bx * 12) * 8192 + w * 2048 + lane * 8;

    f4v acc[4][4];
    #pragma unroll
    for (int mi = 0; mi < 4; ++mi)
        #pragma unroll
        for (int ni = 0; ni < 4; ++ni) acc[mi][ni] = (f4v){0.f,0.f,0.f,0.f};

    for (int s = 0; s < 12; ++s) {
        __syncthreads();
        #pragma unroll
        for (int it = 0; it < 4; ++it) {
            gld_lds16(Ap + it * 512, &Als[w * 2048 + it * 512]);
            gld_lds16(Bp + it * 512, &Bls[w * 2048 + it * 512]);
        }
        Ap += 8192; Bp += 8192;
        __syncthreads();
        #pragma unroll
        for (int kk = 0; kk < 2; ++kk) {
            const int col = ((kk * 4 + q) ^ (ln & 7)) * 8;
            s8v af[4], bf[4];
            #pragma unroll
            for (int mi = 0; mi < 4; ++mi)
                af[mi] = *(const s8v*)&Als[(wm * 64 + mi * 16 + ln) * 64 + col];
            #pragma unroll
            for (int ni = 0; ni < 4; ++ni)
                bf[ni] = *(const s8v*)&Bls[(wn * 64 + ni * 16 + ln) * 64 + col];
            #pragma unroll
            for (int mi = 0; mi < 4; ++mi)
                #pragma unroll
                for (int ni = 0; ni < 4; ++ni)
                    acc[mi][ni] = __builtin_amdgcn_mfma_f32_16x16x32_bf16(
                        af[mi], bf[ni], acc[mi][ni], 0, 0, 0);
        }
    }

    // epilogue -> hg tile (bx, kc = by*2 + wm), row = entry, swizzled f chunks
    const float* b1e = b1 + (size_t)e * F_DIM + by * 128 + wm * 64;
    u16* ht = hg + ((size_t)bx * 48 + by * 2 + wm) * 8192;
    #pragma unroll
    for (int ni = 0; ni < 4; ++ni) {
        const int rr = wn * 64 + ni * 16 + ln;
        #pragma unroll
        for (int mi = 0; mi < 4; ++mi) {
            const float4 bv = *(const float4*)&b1e[mi * 16 + q * 4];
            u16 us[4];
            us[0] = f2bf(gelu_exact(acc[mi][ni][0] + bv.x));
            us[1] = f2bf(gelu_exact(acc[mi][ni][1] + bv.y));
            us[2] = f2bf(gelu_exact(acc[mi][ni][2] + bv.z));
            us[3] = f2bf(gelu_exact(acc[mi][ni][3] + bv.w));
            uint2 pk;
            pk.x = (u32)us[0] | ((u32)us[1] << 16);
            pk.y = (u32)us[2] | ((u32)us[3] << 16);
            const int c8 = mi * 2 + (q >> 1);
            *(uint2*)&ht[rr * 64 + ((c8 ^ (rr & 7)) * 8) + (q & 1) * 4] = pk;
        }
    }
}

// ---------------------------------------------------------------------------
// Stage 2: per (entry-tile, d-tile): C[m=d 128][n=entry 128], K=3072 (48 steps).
// ---------------------------------------------------------------------------
__global__ __launch_bounds__(256) void s2_gemm(
    const u16* __restrict__ hg, const u16* __restrict__ w2g,
    const int* __restrict__ counts, const int* __restrict__ te,
    const int* __restrict__ tb, const int* __restrict__ ntile,
    const int* __restrict__ tokbuf, const float* __restrict__ gatebuf,
    float* __restrict__ y)
{
    __shared__ u16 Als[8192];
    __shared__ u16 Bls[8192];
    __shared__ int   sts[128];
    __shared__ float sg[128];
    const int bx = blockIdx.x, by = blockIdx.y;
    if (bx >= *ntile) return;
    const int e = te[bx], base = tb[bx], cnt = counts[e];

    const int tid  = threadIdx.x;
    const int w    = tid >> 6;
    const int lane = tid & 63;
    const int wm   = w & 1, wn = w >> 1;
    const int q    = lane >> 4, ln = lane & 15;

    if (tid < 128) {
        const int ent = base + tid;
        const bool v = ent < cnt;
        sts[tid] = v ? tokbuf[(size_t)e * CAP + ent] : -1;
        sg[tid]  = v ? gatebuf[(size_t)e * CAP + ent] : 0.f;
    }

    const u16* Ap = w2g + ((size_t)(e * 6 + by) * 48) * 8192 + w * 2048 + lane * 8;
    const u16* Bp = hg  + ((size_t)bx * 48) * 8192 + w * 2048 + lane * 8;

    f4v acc[4][4];
    #pragma unroll
    for (int mi = 0; mi < 4; ++mi)
        #pragma unroll
        for (int ni = 0; ni < 4; ++ni) acc[mi][ni] = (f4v){0.f,0.f,0.f,0.f};

    for (int s = 0; s < 48; ++s) {
        __syncthreads();
        #pragma unroll
        for (int it = 0; it < 4; ++it) {
            gld_lds16(Ap + it * 512, &Als[w * 2048 + it * 512]);
            gld_lds16(Bp + it * 512, &Bls[w * 2048 + it * 512]);
        }
        Ap += 8192; Bp += 8192;
        __syncthreads();
        #pragma unroll
        for (int kk = 0; kk < 2; ++kk) {
            const int col = ((kk * 4 + q) ^ (ln & 7)) * 8;
            s8v af[4], bf[4];
            #pragma unroll
            for (int mi = 0; mi < 4; ++mi)
                af[mi] = *(const s8v*)&Als[(wm * 64 + mi * 16 + ln) * 64 + col];
            #pragma unroll
            for (int ni = 0; ni < 4; ++ni)
                bf[ni] = *(const s8v*)&Bls[(wn * 64 + ni * 16 + ln) * 64 + col];
            #pragma unroll
            for (int mi = 0; mi < 4; ++mi)
                #pragma unroll
                for (int ni = 0; ni < 4; ++ni)
                    acc[mi][ni] = __builtin_amdgcn_mfma_f32_16x16x32_bf16(
                        af[mi], bf[ni], acc[mi][ni], 0, 0, 0);
        }
    }

    #pragma unroll
    for (int ni = 0; ni < 4; ++ni) {
        const int rr = wn * 64 + ni * 16 + ln;
        const int ts = sts[rr];
        if (ts >= 0) {
            const float g = sg[rr];
            float* yr = y + (size_t)ts * D_DIM + by * 128 + wm * 64;
            #pragma unroll
            for (int mi = 0; mi < 4; ++mi) {
                float4 o;
                o.x = g * acc[mi][ni][0];
                o.y = g * acc[mi][ni][1];
                o.z = g * acc[mi][ni][2];
                o.w = g * acc[mi][ni][3];
                *(float4*)&yr[mi * 16 + q * 4] = o;
            }
        }
    }
}

// out = g0*b2[i0] + g1*b2[i1] + y[2t] + y[2t+1]
__global__ __launch_bounds__(256) void combine_kernel(
    const float* __restrict__ y, const u32* __restrict__ rec_idx,
    const float2* __restrict__ rec_g, const float* __restrict__ b2,
    float* __restrict__ out)
{
    const int gid = blockIdx.x * 256 + threadIdx.x;
    const int t = gid / 192;
    const int c = (gid - t * 192) * 4;
    const u32 pk = rec_idx[t];
    const int i0 = pk & 15, i1 = (pk >> 4) & 15;
    const float2 g = rec_g[t];
    const float4 a  = *(const float4*)&y[(size_t)(2 * t) * D_DIM + c];
    const float4 b  = *(const float4*)&y[(size_t)(2 * t + 1) * D_DIM + c];
    const float4 ba = *(const float4*)&b2[(size_t)i0 * D_DIM + c];
    const float4 bb = *(const float4*)&b2[(size_t)i1 * D_DIM + c];
    float4 o;
    o.x = g.x * ba.x + g.y * bb.x + a.x + b.x;
    o.y = g.x * ba.y + g.y * bb.y + a.y + b.y;
    o.z = g.x * ba.z + g.y * bb.z + a.z + b.z;
    o.w = g.x * ba.w + g.y * bb.w + a.w + b.w;
    *(float4*)&out[(size_t)t * D_DIM + c] = o;
}

// ---------------------------------------------------------------------------
extern "C" void kernel_launch(void* const* d_in, const int* in_sizes, int n_in,
                              void* d_out, int out_size, void* d_ws, size_t ws_size,
                              hipStream_t stream) {
    const float* x  = (const float*)d_in[0];
    const float* Wg = (const float*)d_in[1];
    const float* bg = (const float*)d_in[2];
    const float* W1 = (const float*)d_in[3];
    const float* b1 = (const float*)d_in[4];
    const float* W2 = (const float*)d_in[5];
    const float* b2 = (const float*)d_in[6];
    float* out = (float*)d_out;

    // ws layout (~260 MB)
    char* ws = (char*)d_ws;
    size_t off = 0;
    u16* xg  = (u16*)(ws + off); off += (size_t)NT_MAX * 12 * 8192 * sizeof(u16);
    u16* w1g = (u16*)(ws + off); off += (size_t)E_EXP * 24 * 12 * 8192 * sizeof(u16);
    u16* w2g = (u16*)(ws + off); off += (size_t)E_EXP * 6 * 48 * 8192 * sizeof(u16);
    u16* hg  = (u16*)(ws + off); off += (size_t)NT_MAX * 48 * 8192 * sizeof(u16);
    float* y = (float*)(ws + off); off += (size_t)2 * N_TOK * D_DIM * sizeof(float);
    int* tokbuf = (int*)(ws + off);      off += (size_t)E_EXP * CAP * sizeof(int);
    float* gatebuf = (float*)(ws + off); off += (size_t)E_EXP * CAP * sizeof(float);
    u32* rec_idx = (u32*)(ws + off);     off += (size_t)N_TOK * sizeof(u32);
    float2* rec_g = (float2*)(ws + off); off += (size_t)N_TOK * sizeof(float2);
    int* counts = (int*)(ws + off);      off += 64;
    int* te     = (int*)(ws + off);      off += NT_MAX * sizeof(int);
    int* tb     = (int*)(ws + off);      off += NT_MAX * sizeof(int);
    int* ntile  = (int*)(ws + off);      off += 64;

    hipMemsetAsync(counts, 0, E_EXP * sizeof(int), stream);

    moe_gates<<<N_TOK / 4, 256, 0, stream>>>(x, Wg, bg, rec_idx, rec_g);
    moe_scatter<<<N_TOK / 256, 256, 0, stream>>>(rec_idx, rec_g, counts, tokbuf, gatebuf);
    scan_kernel<<<1, 64, 0, stream>>>(counts, te, tb, ntile);
    pack_w<<<dim3(24, 12, E_EXP), 256, 0, stream>>>(W1, w1g, D_DIM, F_DIM);
    pack_w<<<dim3(6, 48, E_EXP), 256, 0, stream>>>(W2, w2g, F_DIM, D_DIM);
    pack_x<<<dim3(NT_MAX, 12), 256, 0, stream>>>(x, counts, te, tb, ntile, tokbuf, xg);

    s1_gemm<<<dim3(NT_MAX, 24), 256, 0, stream>>>(xg, w1g, b1, te, ntile, hg);
    s2_gemm<<<dim3(NT_MAX, 6), 256, 0, stream>>>(hg, w2g, counts, te, tb, ntile,
                                                 tokbuf, gatebuf, y);
    combine_kernel<<<(N_TOK * 192) / 256, 256, 0, stream>>>(y, rec_idx, rec_g, b2, out);
}

// Round 5
// 537.079 us; speedup vs baseline: 3.6996x; 1.0464x over previous
//
#include <hip/hip_runtime.h>
#include <hip/hip_bf16.h>

// MoE: B=4,T=2048,D=768,E=8,F=3072,K=2.  N=8192 tokens, 16384 entries.
// Pipeline (7 launches):
//   prep      -> gates (rec_idx/rec_g) | pack W1 (256-row tiles) | pack W2
//                (128-row tiles) | zero counts, fused in one grid
//   scatter   -> buckets via wave-ballot aggregation (<=1024 atomics)
//   scan      -> tile table (expert, base) for <=136 entry-tiles
//   pack_x    -> gathered x as swizzled [128][64] tiles (s1 B operand)
//   s1        -> 256(f)x128(entry) tile GEMM, GELU fused, hg in s2-B layout
//   s2        -> 128(d)x128(entry) tile GEMM, y bf16 (no atomics)
//   combine   -> out = g0*b2[i0] + g1*b2[i1] + y[2t] + y[2t+1]

#define N_TOK 8192
#define D_DIM 768
#define E_EXP 8
#define F_DIM 3072
#define CAP   8192
#define NT_MAX 136          // max entry tiles: 16384/128 + 8 ceil slack

typedef __attribute__((ext_vector_type(8))) short s8v;   // 8 x bf16
typedef __attribute__((ext_vector_type(4))) float f4v;   // MFMA acc
typedef unsigned short u16;
typedef unsigned int   u32;
typedef unsigned long long u64;

static __device__ __forceinline__ u16 f2bf(float f) {
    u32 u = __float_as_uint(f);
    return (u16)((u + 0x7fffu + ((u >> 16) & 1u)) >> 16);   // RNE
}
static __device__ __forceinline__ float bf2f(u16 v) {
    return __uint_as_float((u32)v << 16);
}
static __device__ __forceinline__ float gelu_exact(float v) {
    return 0.5f * v * (1.0f + erff(v * 0.70710678118654752440f));
}
static __device__ __forceinline__ void gld_lds16(const u16* g, u16* l) {
    __builtin_amdgcn_global_load_lds(
        (const __attribute__((address_space(1))) void*)g,
        (__attribute__((address_space(3))) void*)l, 16, 0, 0);
}

// ---------------------------------------------------------------------------
// Fused prep: block ranges do independent jobs.
//   [0,2048)      gates: 4 tokens/block (wave per token)
//   [2048,4352)   pack W1 -> w1g, 256-row tiles (ntm=12, KC=12)
//   [4352,6656)   pack W2 -> w2g, 128-row tiles (ntm=6,  KC=48)
//   block 0 also zeros counts (scatter runs in a later kernel).
// ---------------------------------------------------------------------------
__device__ __forceinline__ void pack_w_body(
    const float* __restrict__ src, u16* __restrict__ dst,
    int rt, int kc, int e, int K1, int M2, int KC, int TR, int ntm)
{
    __shared__ float ls[64][132];
    const float* se = src + (size_t)e * K1 * M2;
    const int tid = threadIdx.x;

    const int kr = tid >> 2, mq = tid & 3;
    const float* srow = se + (size_t)(kc * 64 + kr) * M2 + rt * 128 + mq * 32;
    #pragma unroll
    for (int it = 0; it < 8; ++it)
        *(float4*)&ls[kr][mq * 32 + it * 4] = *(const float4*)(srow + it * 4);
    __syncthreads();

    u16* dt_ = dst + ((size_t)(e * ntm + (rt * 128) / TR) * KC + kc) * ((size_t)TR * 64)
                   + (size_t)((rt * 128) % TR) * 64;
    const int rr = tid >> 1, hf = tid & 1;
    #pragma unroll
    for (int j = 0; j < 4; ++j) {
        const int c8 = hf * 4 + j;
        union { s8v v; u16 u[8]; } o;
        #pragma unroll
        for (int jj = 0; jj < 8; ++jj) o.u[jj] = f2bf(ls[c8 * 8 + jj][rr]);
        *(s8v*)&dt_[rr * 64 + ((c8 ^ (rr & 7)) * 8)] = o.v;
    }
}

__global__ __launch_bounds__(256) void prep_kernel(
    const float* __restrict__ x, const float* __restrict__ Wg,
    const float* __restrict__ bg, const float* __restrict__ W1,
    const float* __restrict__ W2, u32* __restrict__ rec_idx,
    float2* __restrict__ rec_g, u16* __restrict__ w1g,
    u16* __restrict__ w2g, int* __restrict__ counts)
{
    const int bid = blockIdx.x;
    if (bid == 0 && threadIdx.x < E_EXP) counts[threadIdx.x] = 0;

    if (bid < 2048) {
        // ------- gates -------
        const int wave = threadIdx.x >> 6;
        const int lane = threadIdx.x & 63;
        const int t = bid * 4 + wave;

        float acc[8];
        #pragma unroll
        for (int e = 0; e < 8; ++e) acc[e] = 0.f;

        const float* xrow = x + (size_t)t * D_DIM + lane * 12;
        #pragma unroll
        for (int i = 0; i < 3; ++i) {
            float4 xv = *(const float4*)(xrow + i * 4);
            float xs[4] = {xv.x, xv.y, xv.z, xv.w};
            #pragma unroll
            for (int j = 0; j < 4; ++j) {
                const int d = lane * 12 + i * 4 + j;
                const float4 w0 = *(const float4*)(Wg + (size_t)d * 8);
                const float4 w1 = *(const float4*)(Wg + (size_t)d * 8 + 4);
                acc[0] += xs[j] * w0.x;  acc[1] += xs[j] * w0.y;
                acc[2] += xs[j] * w0.z;  acc[3] += xs[j] * w0.w;
                acc[4] += xs[j] * w1.x;  acc[5] += xs[j] * w1.y;
                acc[6] += xs[j] * w1.z;  acc[7] += xs[j] * w1.w;
            }
        }
        #pragma unroll
        for (int e = 0; e < 8; ++e) {
            float v = acc[e];
            #pragma unroll
            for (int off = 32; off > 0; off >>= 1) v += __shfl_xor(v, off, 64);
            acc[e] = v + bg[e];
        }
        if (lane == 0) {
            float mx = acc[0];
            #pragma unroll
            for (int e = 1; e < 8; ++e) mx = fmaxf(mx, acc[e]);
            float p[8], s = 0.f;
            #pragma unroll
            for (int e = 0; e < 8; ++e) { p[e] = expf(acc[e] - mx); s += p[e]; }
            const float inv = 1.f / s;
            #pragma unroll
            for (int e = 0; e < 8; ++e) p[e] *= inv;

            int i0 = 0; float g0 = p[0];
            #pragma unroll
            for (int e = 1; e < 8; ++e) if (p[e] > g0) { g0 = p[e]; i0 = e; }
            int i1 = -1; float g1 = -1.f;
            #pragma unroll
            for (int e = 0; e < 8; ++e) if (e != i0 && p[e] > g1) { g1 = p[e]; i1 = e; }

            rec_idx[t] = (u32)i0 | ((u32)i1 << 4);
            rec_g[t] = make_float2(g0, g1);
        }
    } else if (bid < 4352) {
        // ------- pack W1: [E][768][3072] -> 256-row tiles -------
        const int id = bid - 2048;               // e*288 + rt*12 + kc
        const int e = id / 288, rem = id - e * 288;
        const int rt = rem / 12, kc = rem - rt * 12;
        pack_w_body(W1, w1g, rt, kc, e, D_DIM, F_DIM, 12, 256, 12);
    } else {
        // ------- pack W2: [E][3072][768] -> 128-row tiles -------
        const int id = bid - 4352;               // e*288 + rt*48 + kc
        const int e = id / 288, rem = id - e * 288;
        const int rt = rem / 48, kc = rem - rt * 48;
        pack_w_body(W2, w2g, rt, kc, e, F_DIM, D_DIM, 48, 128, 6);
    }
}

// ---------------------------------------------------------------------------
// Scatter: thread per token, wave-ballot aggregation -> <=8 atomics/wave.
// ---------------------------------------------------------------------------
__global__ __launch_bounds__(256) void moe_scatter(
    const u32* __restrict__ rec_idx, const float2* __restrict__ rec_g,
    int* __restrict__ counts, int* __restrict__ tokbuf,
    float* __restrict__ gatebuf)
{
    const int t = blockIdx.x * 256 + threadIdx.x;
    const int lane = threadIdx.x & 63;
    const u32 pk = rec_idx[t];
    const int i0 = pk & 15, i1 = (pk >> 4) & 15;
    const float2 g = rec_g[t];
    const u64 lmask = ((u64)1 << lane) - 1;

    #pragma unroll
    for (int e = 0; e < 8; ++e) {
        const u64 m0 = __ballot(i0 == e);
        const u64 m1 = __ballot(i1 == e);
        const int c0 = __popcll(m0);
        const int total = c0 + __popcll(m1);
        if (total > 0) {
            int base = 0;
            if (lane == 0) base = atomicAdd(&counts[e], total);
            base = __shfl(base, 0, 64);
            if (i0 == e) {
                const int p = base + __popcll(m0 & lmask);
                tokbuf[(size_t)e * CAP + p] = 2 * t;
                gatebuf[(size_t)e * CAP + p] = g.x;
            }
            if (i1 == e) {
                const int p = base + c0 + __popcll(m1 & lmask);
                tokbuf[(size_t)e * CAP + p] = 2 * t + 1;
                gatebuf[(size_t)e * CAP + p] = g.y;
            }
        }
    }
}

// tile table: for each expert, one tile per 128 entries
__global__ void scan_kernel(const int* __restrict__ counts,
                            int* __restrict__ te, int* __restrict__ tb,
                            int* __restrict__ ntile) {
    if (threadIdx.x == 0) {
        int nt = 0;
        for (int e = 0; e < E_EXP; ++e)
            for (int k = 0; k * 128 < counts[e]; ++k) {
                te[nt] = e; tb[nt] = k * 128; ++nt;
            }
        *ntile = nt;
    }
}

// ---------------------------------------------------------------------------
// pack_x: gather token rows -> swizzled bf16 [128][64] tiles (s1 B operand).
// ---------------------------------------------------------------------------
__global__ __launch_bounds__(256) void pack_x(
    const float* __restrict__ x, const int* __restrict__ counts,
    const int* __restrict__ te, const int* __restrict__ tb,
    const int* __restrict__ ntile, const int* __restrict__ tokbuf,
    u16* __restrict__ xg)
{
    const int bx = blockIdx.x, kc = blockIdx.y;
    if (bx >= *ntile) return;
    const int e = te[bx], base = tb[bx], cnt = counts[e];
    const int tid = threadIdx.x;
    const int r = tid >> 1, hf = tid & 1;
    int ent = base + r; if (ent >= cnt) ent = cnt - 1;
    const int tok = tokbuf[(size_t)e * CAP + ent] >> 1;
    const float* xr = x + (size_t)tok * D_DIM + kc * 64 + hf * 32;
    u16* xt = xg + ((size_t)bx * 12 + kc) * 8192 + r * 64;
    #pragma unroll
    for (int j = 0; j < 4; ++j) {
        float4 a = *(const float4*)(xr + j * 8);
        float4 b = *(const float4*)(xr + j * 8 + 4);
        union { s8v v; u16 u[8]; } o;
        o.u[0] = f2bf(a.x); o.u[1] = f2bf(a.y); o.u[2] = f2bf(a.z); o.u[3] = f2bf(a.w);
        o.u[4] = f2bf(b.x); o.u[5] = f2bf(b.y); o.u[6] = f2bf(b.z); o.u[7] = f2bf(b.w);
        *(s8v*)&xt[((hf * 4 + j) ^ (r & 7)) * 8] = o.v;
    }
}

// ---------------------------------------------------------------------------
// Stage 1: per (entry-tile, f-tile256): C[m=f 256][n=entry 128], K=768.
// A tile 256x64 (32 KB), B tile 128x64 (16 KB) per step; 12 steps.
// Wave w: wm=w&1 -> M half (128 f), wn=w>>1 -> N quarter (64 entries).
// acc[8][4] (128 AGPR).  Epilogue: bias+GELU -> bf16 hg in s2-B layout.
// ---------------------------------------------------------------------------
__global__ __launch_bounds__(256, 2) void s1_gemm(
    const u16* __restrict__ xg, const u16* __restrict__ w1g,
    const float* __restrict__ b1, const int* __restrict__ te,
    const int* __restrict__ ntile, u16* __restrict__ hg)
{
    __shared__ u16 Als[16384];   // 256 rows x 64
    __shared__ u16 Bls[8192];    // 128 rows x 64
    const int bx = blockIdx.x, by = blockIdx.y;   // by in [0,12): 256 f
    if (bx >= *ntile) return;
    const int e = te[bx];

    const int tid  = threadIdx.x;
    const int w    = tid >> 6;
    const int lane = tid & 63;
    const int wm   = w & 1, wn = w >> 1;
    const int q    = lane >> 4, ln = lane & 15;

    const u16* Ap = w1g + ((size_t)(e * 12 + by) * 12) * 16384 + w * 4096 + lane * 8;
    const u16* Bp = xg  + ((size_t)bx * 12) * 8192 + w * 2048 + lane * 8;

    f4v acc[8][4];
    #pragma unroll
    for (int mi = 0; mi < 8; ++mi)
        #pragma unroll
        for (int ni = 0; ni < 4; ++ni) acc[mi][ni] = (f4v){0.f,0.f,0.f,0.f};

    for (int s = 0; s < 12; ++s) {
        __syncthreads();
        #pragma unroll
        for (int it = 0; it < 8; ++it)
            gld_lds16(Ap + it * 512, &Als[w * 4096 + it * 512]);
        #pragma unroll
        for (int it = 0; it < 4; ++it)
            gld_lds16(Bp + it * 512, &Bls[w * 2048 + it * 512]);
        Ap += 16384; Bp += 8192;
        __syncthreads();
        #pragma unroll
        for (int kk = 0; kk < 2; ++kk) {
            const int col = ((kk * 4 + q) ^ (ln & 7)) * 8;
            s8v af[8], bf[4];
            #pragma unroll
            for (int mi = 0; mi < 8; ++mi)
                af[mi] = *(const s8v*)&Als[(wm * 128 + mi * 16 + ln) * 64 + col];
            #pragma unroll
            for (int ni = 0; ni < 4; ++ni)
                bf[ni] = *(const s8v*)&Bls[(wn * 64 + ni * 16 + ln) * 64 + col];
            #pragma unroll
            for (int mi = 0; mi < 8; ++mi)
                #pragma unroll
                for (int ni = 0; ni < 4; ++ni)
                    acc[mi][ni] = __builtin_amdgcn_mfma_f32_16x16x32_bf16(
                        af[mi], bf[ni], acc[mi][ni], 0, 0, 0);
        }
    }

    // epilogue: f_local = wm*128 + mi*16 + q*4 (+r), entry = wn*64 + ni*16 + ln
    const float* b1e = b1 + (size_t)e * F_DIM + by * 256;
    #pragma unroll
    for (int mi = 0; mi < 8; ++mi) {
        const int floc = wm * 128 + mi * 16 + q * 4;
        const int kc   = by * 4 + wm * 2 + (mi >> 2);
        const int c8   = (mi & 3) * 2 + (q >> 1);
        const float4 bv = *(const float4*)&b1e[floc];
        u16* ht = hg + ((size_t)bx * 48 + kc) * 8192;
        #pragma unroll
        for (int ni = 0; ni < 4; ++ni) {
            const int rr = wn * 64 + ni * 16 + ln;
            u16 us[4];
            us[0] = f2bf(gelu_exact(acc[mi][ni][0] + bv.x));
            us[1] = f2bf(gelu_exact(acc[mi][ni][1] + bv.y));
            us[2] = f2bf(gelu_exact(acc[mi][ni][2] + bv.z));
            us[3] = f2bf(gelu_exact(acc[mi][ni][3] + bv.w));
            uint2 pk;
            pk.x = (u32)us[0] | ((u32)us[1] << 16);
            pk.y = (u32)us[2] | ((u32)us[3] << 16);
            *(uint2*)&hg[((size_t)bx * 48 + kc) * 8192 +
                         rr * 64 + ((c8 ^ (rr & 7)) * 8) + (q & 1) * 4] = pk;
        }
        (void)ht;
    }
}

// ---------------------------------------------------------------------------
// Stage 2: per (entry-tile, d-tile): C[m=d 128][n=entry 128], K=3072 (48 steps).
// Epilogue: y[tokslot][d] = gate * C  (bf16 stores, no atomics).
// ---------------------------------------------------------------------------
__global__ __launch_bounds__(256) void s2_gemm(
    const u16* __restrict__ hg, const u16* __restrict__ w2g,
    const int* __restrict__ counts, const int* __restrict__ te,
    const int* __restrict__ tb, const int* __restrict__ ntile,
    const int* __restrict__ tokbuf, const float* __restrict__ gatebuf,
    u16* __restrict__ y)
{
    __shared__ u16 Als[8192];
    __shared__ u16 Bls[8192];
    __shared__ int   sts[128];
    __shared__ float sg[128];
    const int bx = blockIdx.x, by = blockIdx.y;
    if (bx >= *ntile) return;
    const int e = te[bx], base = tb[bx], cnt = counts[e];

    const int tid  = threadIdx.x;
    const int w    = tid >> 6;
    const int lane = tid & 63;
    const int wm   = w & 1, wn = w >> 1;
    const int q    = lane >> 4, ln = lane & 15;

    if (tid < 128) {
        const int ent = base + tid;
        const bool v = ent < cnt;
        sts[tid] = v ? tokbuf[(size_t)e * CAP + ent] : -1;
        sg[tid]  = v ? gatebuf[(size_t)e * CAP + ent] : 0.f;
    }

    const u16* Ap = w2g + ((size_t)(e * 6 + by) * 48) * 8192 + w * 2048 + lane * 8;
    const u16* Bp = hg  + ((size_t)bx * 48) * 8192 + w * 2048 + lane * 8;

    f4v acc[4][4];
    #pragma unroll
    for (int mi = 0; mi < 4; ++mi)
        #pragma unroll
        for (int ni = 0; ni < 4; ++ni) acc[mi][ni] = (f4v){0.f,0.f,0.f,0.f};

    for (int s = 0; s < 48; ++s) {
        __syncthreads();
        #pragma unroll
        for (int it = 0; it < 4; ++it) {
            gld_lds16(Ap + it * 512, &Als[w * 2048 + it * 512]);
            gld_lds16(Bp + it * 512, &Bls[w * 2048 + it * 512]);
        }
        Ap += 8192; Bp += 8192;
        __syncthreads();
        #pragma unroll
        for (int kk = 0; kk < 2; ++kk) {
            const int col = ((kk * 4 + q) ^ (ln & 7)) * 8;
            s8v af[4], bf[4];
            #pragma unroll
            for (int mi = 0; mi < 4; ++mi)
                af[mi] = *(const s8v*)&Als[(wm * 64 + mi * 16 + ln) * 64 + col];
            #pragma unroll
            for (int ni = 0; ni < 4; ++ni)
                bf[ni] = *(const s8v*)&Bls[(wn * 64 + ni * 16 + ln) * 64 + col];
            #pragma unroll
            for (int mi = 0; mi < 4; ++mi)
                #pragma unroll
                for (int ni = 0; ni < 4; ++ni)
                    acc[mi][ni] = __builtin_amdgcn_mfma_f32_16x16x32_bf16(
                        af[mi], bf[ni], acc[mi][ni], 0, 0, 0);
        }
    }

    #pragma unroll
    for (int ni = 0; ni < 4; ++ni) {
        const int rr = wn * 64 + ni * 16 + ln;
        const int ts = sts[rr];
        if (ts >= 0) {
            const float g = sg[rr];
            u16* yr = y + (size_t)ts * D_DIM + by * 128 + wm * 64;
            #pragma unroll
            for (int mi = 0; mi < 4; ++mi) {
                u16 us[4];
                us[0] = f2bf(g * acc[mi][ni][0]);
                us[1] = f2bf(g * acc[mi][ni][1]);
                us[2] = f2bf(g * acc[mi][ni][2]);
                us[3] = f2bf(g * acc[mi][ni][3]);
                uint2 pk;
                pk.x = (u32)us[0] | ((u32)us[1] << 16);
                pk.y = (u32)us[2] | ((u32)us[3] << 16);
                *(uint2*)&yr[mi * 16 + q * 4] = pk;
            }
        }
    }
}

// out = g0*b2[i0] + g1*b2[i1] + y[2t] + y[2t+1]
__global__ __launch_bounds__(256) void combine_kernel(
    const u16* __restrict__ y, const u32* __restrict__ rec_idx,
    const float2* __restrict__ rec_g, const float* __restrict__ b2,
    float* __restrict__ out)
{
    const int gid = blockIdx.x * 256 + threadIdx.x;
    const int t = gid / 192;
    const int c = (gid - t * 192) * 4;
    const u32 pk = rec_idx[t];
    const int i0 = pk & 15, i1 = (pk >> 4) & 15;
    const float2 g = rec_g[t];
    union { uint2 p; u16 u[4]; } a, b;
    a.p = *(const uint2*)&y[(size_t)(2 * t) * D_DIM + c];
    b.p = *(const uint2*)&y[(size_t)(2 * t + 1) * D_DIM + c];
    const float4 ba = *(const float4*)&b2[(size_t)i0 * D_DIM + c];
    const float4 bb = *(const float4*)&b2[(size_t)i1 * D_DIM + c];
    float4 o;
    o.x = g.x * ba.x + g.y * bb.x + bf2f(a.u[0]) + bf2f(b.u[0]);
    o.y = g.x * ba.y + g.y * bb.y + bf2f(a.u[1]) + bf2f(b.u[1]);
    o.z = g.x * ba.z + g.y * bb.z + bf2f(a.u[2]) + bf2f(b.u[2]);
    o.w = g.x * ba.w + g.y * bb.w + bf2f(a.u[3]) + bf2f(b.u[3]);
    *(float4*)&out[(size_t)t * D_DIM + c] = o;
}

// ---------------------------------------------------------------------------
extern "C" void kernel_launch(void* const* d_in, const int* in_sizes, int n_in,
                              void* d_out, int out_size, void* d_ws, size_t ws_size,
                              hipStream_t stream) {
    const float* x  = (const float*)d_in[0];
    const float* Wg = (const float*)d_in[1];
    const float* bg = (const float*)d_in[2];
    const float* W1 = (const float*)d_in[3];
    const float* b1 = (const float*)d_in[4];
    const float* W2 = (const float*)d_in[5];
    const float* b2 = (const float*)d_in[6];
    float* out = (float*)d_out;

    // ws layout (~235 MB)
    char* ws = (char*)d_ws;
    size_t off = 0;
    u16* xg  = (u16*)(ws + off); off += (size_t)NT_MAX * 12 * 8192 * sizeof(u16);
    u16* w1g = (u16*)(ws + off); off += (size_t)E_EXP * F_DIM * D_DIM * sizeof(u16);
    u16* w2g = (u16*)(ws + off); off += (size_t)E_EXP * D_DIM * F_DIM * sizeof(u16);
    u16* hg  = (u16*)(ws + off); off += (size_t)NT_MAX * 48 * 8192 * sizeof(u16);
    u16* y   = (u16*)(ws + off); off += (size_t)2 * N_TOK * D_DIM * sizeof(u16);
    int* tokbuf = (int*)(ws + off);      off += (size_t)E_EXP * CAP * sizeof(int);
    float* gatebuf = (float*)(ws + off); off += (size_t)E_EXP * CAP * sizeof(float);
    u32* rec_idx = (u32*)(ws + off);     off += (size_t)N_TOK * sizeof(u32);
    float2* rec_g = (float2*)(ws + off); off += (size_t)N_TOK * sizeof(float2);
    int* counts = (int*)(ws + off);      off += 64;
    int* te     = (int*)(ws + off);      off += NT_MAX * sizeof(int);
    int* tb     = (int*)(ws + off);      off += NT_MAX * sizeof(int);
    int* ntile  = (int*)(ws + off);      off += 64;

    prep_kernel<<<6656, 256, 0, stream>>>(x, Wg, bg, W1, W2, rec_idx, rec_g,
                                          w1g, w2g, counts);
    moe_scatter<<<N_TOK / 256, 256, 0, stream>>>(rec_idx, rec_g, counts, tokbuf, gatebuf);
    scan_kernel<<<1, 64, 0, stream>>>(counts, te, tb, ntile);
    pack_x<<<dim3(NT_MAX, 12), 256, 0, stream>>>(x, counts, te, tb, ntile, tokbuf, xg);

    s1_gemm<<<dim3(NT_MAX, 12), 256, 0, stream>>>(xg, w1g, b1, te, ntile, hg);
    s2_gemm<<<dim3(NT_MAX, 6), 256, 0, stream>>>(hg, w2g, counts, te, tb, ntile,
                                                 tokbuf, gatebuf, y);
    combine_kernel<<<(N_TOK * 192) / 256, 256, 0, stream>>>(y, rec_idx, rec_g, b2, out);
}